// Round 11
// baseline (3215.554 us; speedup 1.0000x reference)
//
#include <hip/hip_runtime.h>
#include <cstddef>
#include <cstdint>

// ---------------- constants ----------------
#define NB    2
#define NP    1024    // patches per image
#define DFEAT 256
#define DSTATE 16
#define NEDGE 1984    // grid edges: 31*63 + 31

typedef unsigned short ushortb;

// ---------------- helpers ----------------
__device__ __forceinline__ float bf2f(unsigned short u){
  union { unsigned int i; float f; } c; c.i = ((unsigned int)u) << 16; return c.f;
}
__device__ __forceinline__ unsigned short f2bf(float f){
  union { float f; unsigned int i; } c; c.f = f;
  unsigned int u = c.i;
  unsigned int r = (u + 0x7fffu + ((u >> 16) & 1u)) >> 16;
  return (unsigned short)r;
}
// dtype-generic input load: isbf ? bf16[i] : fp32[i]
__device__ __forceinline__ float ldin(const void* p, size_t i, int isbf){
  return isbf ? bf2f(((const ushortb*)p)[i]) : ((const float*)p)[i];
}
__device__ __forceinline__ float gelu_f(float x){
  return 0.5f * x * (1.0f + erff(x * 0.70710678118654752f));
}
__device__ __forceinline__ unsigned int f2sort(float f){
  union { float f; unsigned int i; } c; c.f = f;
  return (c.i & 0x80000000u) ? ~c.i : (c.i | 0x80000000u);
}

// ---------------- ws layout (float element offsets) ----------------
constexpr size_t AL(size_t x){ return (x + 63) & ~(size_t)63; }
constexpr size_t O_W1    = 0;                       // 1728  conv1 w fp32
constexpr size_t O_B1    = AL(O_W1 + 1728);         // 64
constexpr size_t O_W2    = AL(O_B1 + 64);           // 73728 conv2 w fp32, layout [g][ic][ocl][9]
constexpr size_t O_B2    = AL(O_W2 + 73728);        // 128
constexpr size_t O_FCW   = AL(O_B2 + 128);          // 32768 [df][128]
constexpr size_t O_FCB   = AL(O_FCW + 32768);       // 256
constexpr size_t O_WDW   = AL(O_FCB + 256);         // 65536 [df][256]
constexpr size_t O_WDB   = AL(O_WDW + 65536);       // 256
constexpr size_t O_BWO   = AL(O_WDB + 256);         // 4096 [s][256]
constexpr size_t O_BBO   = AL(O_BWO + 4096);        // 16
constexpr size_t O_CWO   = AL(O_BBO + 16);          // 4096
constexpr size_t O_CBO   = AL(O_CWO + 4096);        // 16
constexpr size_t O_OW    = AL(O_CBO + 16);          // 65536 [df][256]
constexpr size_t O_OB    = AL(O_OW + 65536);        // 256
constexpr size_t O_AF    = AL(O_OB + 256);          // 4096  A = -exp(A_log), [f][s]
constexpr size_t O_DD    = AL(O_AF + 4096);         // 256
constexpr size_t O_LNG   = AL(O_DD + 256);          // 256
constexpr size_t O_LNB   = AL(O_LNG + 256);         // 256
constexpr size_t O_FEATS = AL(O_LNB + 256);         // 2*1024*256
constexpr size_t O_GPROJ = AL(O_FEATS + (size_t)NB*NP*DFEAT); // 512
constexpr size_t O_GPRIM = AL(O_GPROJ + NB*DFEAT);  // 512
constexpr size_t O_RSEM  = AL(O_GPRIM + NB*DFEAT);  // 2048
constexpr size_t O_BFS   = AL(O_RSEM + NB*NP);      // 2048 (int)
constexpr size_t O_PAR   = AL(O_BFS + NB*NP);       // 2048 (int)
constexpr size_t O_X     = AL(O_PAR + NB*NP);       // 2*1024*256
constexpr size_t O_DELTA = AL(O_X + (size_t)NB*NP*DFEAT);
constexpr size_t O_BP    = AL(O_DELTA + (size_t)NB*NP*DFEAT); // 2*1024*16
constexpr size_t O_CP    = AL(O_BP + NB*NP*DSTATE);
constexpr size_t O_YR    = AL(O_CP + NB*NP*DSTATE); // 2*1024*256
constexpr size_t O_FLAG  = AL(O_YR + (size_t)NB*NP*DFEAT);    // 1 int: is-bf16 flag

// ---------------- K-1: sniff input dtype (bf16 vs fp32) from images buffer -----------
__global__ __launch_bounds__(256) void k_sniff(const void* img, float* ws)
{
  __shared__ int cnt;
  int tid = threadIdx.x;
  if (tid == 0) cnt = 0;
  __syncthreads();
  const ushortb* u = (const ushortb*)img;
  int local = 0;
  for (int k = 0; k < 16; k++){
    unsigned short v = u[tid * 16 + k];
    if (v == 0 || v == 0x8000u){ local++; continue; }
    float f = fabsf(bf2f(v));
    if (f >= 1e-8f && f <= 64.f) local++;    // plausible N(0,1) bf16
  }
  atomicAdd(&cnt, local);
  __syncthreads();
  if (tid == 0) ((int*)(ws + O_FLAG))[0] = (cnt >= 3900) ? 1 : 0;  // >=95% plausible
}

// ---------------- K0: convert weights -> fp32 (conv2 relayout, A=-exp(A_log)) -------
__global__ void k_convert(const void* c1w, const void* c1b, const void* c2w,
                          const void* c2b, const void* fcw, const void* fcb,
                          const void* alog, const void* dvec,
                          const void* bw, const void* bb, const void* cw, const void* cb,
                          const void* wdw, const void* wdb,
                          const void* ow, const void* ob,
                          const void* lng, const void* lnb, float* ws)
{
  const int F = ((const int*)(ws + O_FLAG))[0];
  int i = blockIdx.x * 256 + threadIdx.x;
  if (i < 1728){ ws[O_W1 + i] = ldin(c1w, i, F); return; } i -= 1728;
  if (i < 64){ ws[O_B1 + i] = ldin(c1b, i, F); return; } i -= 64;
  if (i < 73728){
    // dst layout [g=0..15][ic=0..63][ocl=0..7][9]: i = ((g*64+ic)*8+ocl)*9 + t
    // oc = (g>>3)*64 + (g&7)*8 + ocl  (g = h*8 + w in k_patch)
    int g = i / 4608; int r = i - g * 4608;
    int ic = r / 72;  int r2 = r - ic * 72;
    int ocl = r2 / 9; int t = r2 - ocl * 9;
    int oc = (g >> 3) * 64 + (g & 7) * 8 + ocl;
    ws[O_W2 + i] = ldin(c2w, (size_t)(oc * 64 + ic) * 9 + t, F); return;
  } i -= 73728;
  if (i < 128){ ws[O_B2 + i] = ldin(c2b, i, F); return; } i -= 128;
  if (i < 32768){ ws[O_FCW + i] = ldin(fcw, i, F); return; } i -= 32768;
  if (i < 256){ ws[O_FCB + i] = ldin(fcb, i, F); return; } i -= 256;
  if (i < 65536){ ws[O_WDW + i] = ldin(wdw, i, F); return; } i -= 65536;
  if (i < 256){ ws[O_WDB + i] = ldin(wdb, i, F); return; } i -= 256;
  if (i < 4096){ ws[O_BWO + i] = ldin(bw, i, F); return; } i -= 4096;
  if (i < 16){ ws[O_BBO + i] = ldin(bb, i, F); return; } i -= 16;
  if (i < 4096){ ws[O_CWO + i] = ldin(cw, i, F); return; } i -= 4096;
  if (i < 16){ ws[O_CBO + i] = ldin(cb, i, F); return; } i -= 16;
  if (i < 65536){ ws[O_OW + i] = ldin(ow, i, F); return; } i -= 65536;
  if (i < 256){ ws[O_OB + i] = ldin(ob, i, F); return; } i -= 256;
  if (i < 4096){ ws[O_AF + i] = -expf(ldin(alog, i, F)); return; } i -= 4096;
  if (i < 256){ ws[O_DD + i] = ldin(dvec, i, F); return; } i -= 256;
  if (i < 256){ ws[O_LNG + i] = ldin(lng, i, F); return; } i -= 256;
  if (i < 256){ ws[O_LNB + i] = ldin(lnb, i, F); return; }
}

// ---------------- K0b: zero-init YR ----------------
__global__ __launch_bounds__(256) void k_init(float* ws)
{
  size_t i = (size_t)blockIdx.x * 256 + threadIdx.x;
  if (i < (size_t)NB * NP * DFEAT) ws[O_YR + i] = 0.f;
}

// ---------------- K1: per-patch conv1+gelu+conv2+gelu+pool+fc ----------------
// R10 post-mortem: conflicts fixed but dur flat — limiter is latency at 2 blocks/CU
// (Occupancy 44%, VALUBusy 63%). R11: h1 staged in TWO 32-ic halves (sm 64->32 KB,
// total LDS ~36.6 KB) => 4 blocks/CU = 8 waves/SIMD. conv1 recomputed per
// (oc-half, ic-half): 4x conv1 = +7% VALU for 2x latency hiding. Keeps R10's
// bank swizzle x' = (x + y + (y>>2)) & 15 and lane=4px/wave=8oc conv2 shape.
__global__ __launch_bounds__(512, 4) void k_patch(const void* __restrict__ img,
                                                  const float* __restrict__ ws,
                                                  float* __restrict__ feats)
{
  __shared__ float sm[32 * 256];  // 32KB: h1 half [32 ic][16 rows][16 swizzled cols]
  __shared__ float timg[768];     // 3KB input tile [3 c][256 px]
  __shared__ float pool[128];     // pooled sums per oc
  __shared__ float pm[128];       // pooled mean
  const int F = ((const int*)(ws + O_FLAG))[0];
  const float* W1 = ws + O_W1;  const float* B1 = ws + O_B1;
  const float* W2 = ws + O_W2;  const float* B2 = ws + O_B2;
  const float* FCW = ws + O_FCW; const float* FCB = ws + O_FCB;

  int blk = blockIdx.x; int b = blk >> 10; int pidx = blk & 1023;
  int ph = pidx >> 5, pw = pidx & 31;
  int tid = threadIdx.x;

  // stage input tile (16x16x3) into LDS
  if (tid < 256){
    int y = tid >> 4, x = tid & 15;
    #pragma unroll
    for (int c = 0; c < 3; c++)
      timg[c * 256 + tid] =
        ldin(img, (((size_t)b * 3 + c) * 512 + (ph * 16 + y)) * 512 + (pw * 16 + x), F);
  }

  // conv1 thread mapping: (pixel p = tid&255, og = tid>>8 in {0,1}) -> 16 oc each
  int p1 = tid & 255, og1 = tid >> 8;
  int ii1 = p1 >> 4, jj1 = p1 & 15;
  int wadr1 = ii1 * 16 + ((jj1 + ii1 + (ii1 >> 2)) & 15);   // swizzled store addr

  // conv2: wave wv (0..7) x oc-half h (0..1) -> 8 oc; lane = 4 consecutive px in a row
  int wv = tid >> 6, ln = tid & 63;
  int row = ln >> 2, cg = ln & 3;
  int c0 = cg * 4;   // first pixel col of this lane's group

  // precompute swizzled window offsets + validity (ic-invariant)
  int adr2[3][6]; bool okm2[3][6];
  #pragma unroll
  for (int r = 0; r < 3; r++){
    int y = row - 1 + r;
    bool yok = (y >= 0 && y < 16);
    int yy = yok ? y : 0;
    int sw = yy + (yy >> 2);
    #pragma unroll
    for (int cc = 0; cc < 6; cc++){
      int x = c0 - 1 + cc;
      bool ok = yok && (x >= 0) && (x < 16);
      int xx = (x >= 0 && x < 16) ? x : 0;
      adr2[r][cc] = yy * 16 + ((xx + sw) & 15);
      okm2[r][cc] = ok;
    }
  }
  __syncthreads();

  for (int h = 0; h < 2; h++){
    int oc0 = h * 64 + wv * 8;
    float acc[4][8];
    #pragma unroll
    for (int o = 0; o < 8; o++){
      float bz = B2[oc0 + o];
      #pragma unroll
      for (int j = 0; j < 4; j++) acc[j][o] = bz;
    }
    const float* wg = W2 + ((size_t)(h * 8 + wv)) * 4608;   // [ic 0..63][ocl][9]

    for (int q = 0; q < 2; q++){
      // conv1 for ic-half [q*32, q*32+32) -> sm (recomputed per (h,q))
      {
        float pin[27];
        #pragma unroll
        for (int c = 0; c < 3; c++)
          #pragma unroll
          for (int dy = 0; dy < 3; dy++)
            #pragma unroll
            for (int dx = 0; dx < 3; dx++){
              int y = ii1 + dy - 1, x = jj1 + dx - 1;
              bool ok = (y >= 0 && y < 16 && x >= 0 && x < 16);
              pin[c * 9 + dy * 3 + dx] = ok ? timg[c * 256 + y * 16 + x] : 0.f;
            }
        for (int o = 0; o < 16; o++){
          int ocl = og1 * 16 + o;            // 0..31 within half
          int oc = q * 32 + ocl;             // global conv1 channel
          float a = B1[oc];
          #pragma unroll
          for (int t = 0; t < 27; t++) a += W1[oc * 27 + t] * pin[t];
          sm[ocl * 256 + wadr1] = gelu_f(a);
        }
      }
      __syncthreads();
      // conv2 partial over this ic-half
      int icb = 0;
      for (int icl = 0; icl < 32; icl++, icb += 256){
        float win[3][6];
        #pragma unroll
        for (int r = 0; r < 3; r++)
          #pragma unroll
          for (int cc = 0; cc < 6; cc++)
            win[r][cc] = okm2[r][cc] ? sm[icb + adr2[r][cc]] : 0.f;
        const float* wp = wg + (size_t)(q * 32 + icl) * 72;  // 72 wave-uniform floats
        #pragma unroll
        for (int o = 0; o < 8; o++){
          #pragma unroll
          for (int t9 = 0; t9 < 9; t9++){
            int dy = t9 / 3, dx = t9 - dy * 3;
            float wvv = wp[o * 9 + t9];
            #pragma unroll
            for (int j = 0; j < 4; j++)
              acc[j][o] += wvv * win[dy][j + dx];
          }
        }
      }
      __syncthreads();   // conv2 reads done before next conv1 overwrites sm
    }

    // gelu + pool: lane sums its 4 px, wave-reduce over 64 lanes (256 px total)
    #pragma unroll
    for (int o = 0; o < 8; o++){
      float g = gelu_f(acc[0][o]) + gelu_f(acc[1][o]) + gelu_f(acc[2][o]) + gelu_f(acc[3][o]);
      g += __shfl_xor(g, 1);  g += __shfl_xor(g, 2);  g += __shfl_xor(g, 4);
      g += __shfl_xor(g, 8);  g += __shfl_xor(g, 16); g += __shfl_xor(g, 32);
      if (ln == 0) pool[oc0 + o] = g;   // waves own disjoint oc, no merge needed
    }
  }
  __syncthreads();
  if (tid < 128) pm[tid] = pool[tid] * (1.f / 256.f);
  __syncthreads();

  // fc 128 -> 256 (threads 0..255)
  if (tid < 256){
    int df = tid;
    float s = FCB[df];
    const float* wrow = FCW + (size_t)df * 128;
    #pragma unroll
    for (int k = 0; k < 128; k += 4)
      s += wrow[k] * pm[k] + wrow[k + 1] * pm[k + 1]
         + wrow[k + 2] * pm[k + 2] + wrow[k + 3] * pm[k + 3];
    feats[((size_t)(b * 1024 + pidx)) * 256 + df] = s;
  }
}

// ---------------- K2a: g_proj / g_prime, wave-per-row coalesced ----------------------
__global__ __launch_bounds__(256) void k_gmm(const void* __restrict__ lang,
                                             const void* __restrict__ wgate,
                                             const void* __restrict__ wgp,
                                             float* __restrict__ ws)
{
  const int F = ((const int*)(ws + O_FLAG))[0];
  int row = blockIdx.x * 4 + (threadIdx.x >> 6);
  int lane = threadIdx.x & 63;
  int mat = row >> 9;
  int b   = (row >> 8) & 1;
  int df  = row & 255;
  const void* W = mat ? wgp : wgate;
  float s = 0.f;
  for (int k = lane; k < 896; k += 64)
    s += ldin(lang, (size_t)b * 896 + k, F) * ldin(W, (size_t)df * 896 + k, F);
  s += __shfl_xor(s, 1);  s += __shfl_xor(s, 2);  s += __shfl_xor(s, 4);
  s += __shfl_xor(s, 8);  s += __shfl_xor(s, 16); s += __shfl_xor(s, 32);
  if (lane == 0) ws[(mat ? O_GPRIM : O_GPROJ) + b * 256 + df] = s;
}

// ---------------- K2b: r_sem, wave-per-patch ----------------------------------------
__global__ __launch_bounds__(256) void k_rsem(float* __restrict__ ws)
{
  int p2 = blockIdx.x * 4 + (threadIdx.x >> 6);   // 0..2047
  int lane = threadIdx.x & 63;
  int b = p2 >> 10, p = p2 & 1023;
  const float* f = ws + O_FEATS + ((size_t)(b * 1024 + p)) * 256;
  const float* g = ws + O_GPROJ + b * 256;
  float s = 0.f;
  #pragma unroll
  for (int k = 0; k < 4; k++) s += f[lane + 64 * k] * g[lane + 64 * k];
  s += __shfl_xor(s, 1);  s += __shfl_xor(s, 2);  s += __shfl_xor(s, 4);
  s += __shfl_xor(s, 8);  s += __shfl_xor(s, 16); s += __shfl_xor(s, 32);
  if (lane == 0) ws[O_RSEM + p2] = 1.f / (1.f + expf(-s * (1.f / 16.f)));
}

// ---------------- K3: structure (Boruvka MST + weight-ordered adjacency + level BFS) ---
__device__ __forceinline__ void edge_uv(int e, int& u, int& v){
  if (e < 1953){
    int i = e / 63; int k = e - i * 63;
    if (k < 62){ int j = k >> 1; u = i * 32 + j; v = (k & 1) ? u + 32 : u + 1; }
    else { u = i * 32 + 31; v = u + 32; }
  } else { u = 31 * 32 + (e - 1953); v = u + 1; }
}

__global__ __launch_bounds__(1024) void k_struct(float* __restrict__ ws)
{
  __shared__ float s_ninv[1024];
  __shared__ float s_w[NEDGE];
  __shared__ float s_r[1024];
  __shared__ int   s_comp[1024];
  __shared__ int   s_link[1024];
  __shared__ int   s_link2[1024];
  __shared__ unsigned long long s_best[1024];
  __shared__ unsigned char  s_mst[NEDGE];
  __shared__ unsigned short s_adj[1024 * 4];
  __shared__ unsigned char  s_deg[1024];
  __shared__ unsigned short s_bfs[1024];
  __shared__ short          s_parof[1024];
  __shared__ unsigned short s_o2b[1024];
  __shared__ unsigned short s_cur[1024];
  __shared__ unsigned short s_nxt[1024];
  __shared__ unsigned short s_off[1025];
  __shared__ unsigned long long s_rootkey;
  __shared__ int s_ncomp, s_cursz, s_bfscnt, s_nextsz;

  int b = blockIdx.x; int tid = threadIdx.x;
  const float* feats = ws + O_FEATS + (size_t)b * NP * DFEAT;

  // norms, copies, defensive init
  {
    const float4* f4 = (const float4*)(feats + (size_t)tid * 256);
    float d = 0.f;
    for (int k = 0; k < 64; k++){ float4 q = f4[k]; d += q.x*q.x + q.y*q.y + q.z*q.z + q.w*q.w; }
    s_ninv[tid] = 1.f / fmaxf(sqrtf(d), 1e-12f);
    s_r[tid] = ws[O_RSEM + b * NP + tid];
    s_comp[tid] = tid;
    s_deg[tid] = 0;
    s_bfs[tid] = (unsigned short)tid;
    s_o2b[tid] = (unsigned short)tid;
    s_parof[tid] = -1;
  }
  for (int e = tid; e < NEDGE; e += 1024) s_mst[e] = 0;
  __syncthreads();

  // edge weights
  for (int e = tid; e < NEDGE; e += 1024){
    int u, v; edge_uv(e, u, v);
    const float4* fu = (const float4*)(feats + (size_t)u * 256);
    const float4* fv = (const float4*)(feats + (size_t)v * 256);
    float d = 0.f;
    for (int k = 0; k < 64; k++){ float4 a = fu[k], c = fv[k]; d += a.x*c.x + a.y*c.y + a.z*c.z + a.w*c.w; }
    float cosv = d * s_ninv[u] * s_ninv[v];
    s_w[e] = (1.f - s_r[u]) * (1.f - s_r[v]) * (-cosv) + 1e-6f;
  }
  __syncthreads();

  // Boruvka rounds
  for (int round = 0; round < 12; round++){
    s_best[tid] = ~0ull;
    __syncthreads();
    for (int e = tid; e < NEDGE; e += 1024){
      int u, v; edge_uv(e, u, v);
      int cu = s_comp[u], cv = s_comp[v];
      if (cu != cv){
        unsigned long long key = (((unsigned long long)f2sort(s_w[e])) << 32) | (unsigned int)e;
        atomicMin(&s_best[cu], key);
        atomicMin(&s_best[cv], key);
      }
    }
    __syncthreads();
    int l = tid;
    if (s_comp[tid] == tid && s_best[tid] != ~0ull){
      int e = (int)(s_best[tid] & 0xffffffffu);
      int u, v; edge_uv(e, u, v);
      s_mst[e] = 1;
      int cu = s_comp[u], cv = s_comp[v];
      l = (cu == tid) ? cv : cu;
    }
    s_link[tid] = l;
    __syncthreads();
    if (l != tid && s_link[l] == tid && tid < l) s_link[tid] = tid; // break 2-cycles
    __syncthreads();
    for (int it = 0; it < 10; it++){      // pointer jumping (double-buffered)
      int x = s_link[tid]; s_link2[tid] = s_link[x];
      __syncthreads();
      s_link[tid] = s_link2[tid];
      __syncthreads();
    }
    s_comp[tid] = s_link[s_comp[tid]];
    if (tid == 0) s_ncomp = 0;
    __syncthreads();
    if (s_comp[tid] == tid) atomicAdd(&s_ncomp, 1);
    __syncthreads();
    if (s_ncomp == 1) break;
    __syncthreads();
  }
  __syncthreads();

  // weight-ordered adjacency (== Kruskal insertion order for unique MST)
  {
    int v = tid; int i = v >> 5, j = v & 31;
    float wloc[4]; int nloc[4]; int d = 0;
    if (j > 0){ int e = (i < 31) ? (i * 63 + 2 * (j - 1)) : (1953 + (j - 1));
      if (s_mst[e]){ wloc[d] = s_w[e]; nloc[d] = v - 1; d++; } }
    if (j < 31){ int e = (i < 31) ? (i * 63 + 2 * j) : (1953 + j);
      if (s_mst[e]){ wloc[d] = s_w[e]; nloc[d] = v + 1; d++; } }
    if (i > 0){ int e = (i - 1) * 63 + ((j < 31) ? (2 * j + 1) : 62);
      if (s_mst[e]){ wloc[d] = s_w[e]; nloc[d] = v - 32; d++; } }
    if (i < 31){ int e = i * 63 + ((j < 31) ? (2 * j + 1) : 62);
      if (s_mst[e]){ wloc[d] = s_w[e]; nloc[d] = v + 32; d++; } }
    for (int a = 1; a < d; a++){
      float wv = wloc[a]; int nv = nloc[a]; int c = a - 1;
      while (c >= 0 && wloc[c] > wv){ wloc[c+1] = wloc[c]; nloc[c+1] = nloc[c]; c--; }
      wloc[c+1] = wv; nloc[c+1] = nv;
    }
    s_deg[v] = (unsigned char)d;
    for (int a = 0; a < d; a++) s_adj[v * 4 + a] = (unsigned short)nloc[a];
  }
  // root = argmax r (first index on ties)
  if (tid == 0) s_rootkey = 0ull;
  __syncthreads();
  {
    unsigned long long key = (((unsigned long long)f2sort(s_r[tid])) << 32) | (unsigned int)(1023 - tid);
    atomicMax(&s_rootkey, key);
  }
  __syncthreads();
  int root = 1023 - (int)(s_rootkey & 0xffffffffu);

  // level-parallel tree BFS
  if (tid == 0){
    s_bfs[0] = (unsigned short)root; s_o2b[root] = 0; s_parof[root] = -1;
    s_cur[0] = (unsigned short)root; s_cursz = 1; s_bfscnt = 1;
  }
  __syncthreads();
  for (int lev = 0; lev < 1024; lev++){
    int csz = s_cursz;
    if (csz <= 0) break;
    // wave-parallel exclusive scan of child counts
    if (tid < 64){
      int runbase = 0;
      for (int t0 = 0; t0 < csz; t0 += 64){
        int t = t0 + tid;
        int cnt = 0;
        if (t < csz){
          int n = s_cur[t];
          cnt = (int)s_deg[n] - (s_parof[n] >= 0 ? 1 : 0);
        }
        int v = cnt;
        #pragma unroll
        for (int off = 1; off < 64; off <<= 1){
          int u2 = __shfl_up(v, off);
          if (tid >= off) v += u2;
        }
        if (t < csz) s_off[t] = (unsigned short)(runbase + v - cnt);
        runbase += __shfl(v, 63);
      }
      if (tid == 0) s_nextsz = runbase;
    }
    __syncthreads();
    if (tid < csz){
      int n = s_cur[tid]; int base = s_off[tid]; int k = 0;
      int pn = s_parof[n]; int dg = s_deg[n];
      for (int a = 0; a < dg; a++){
        int c = s_adj[n * 4 + a];
        if (c == pn) continue;
        s_parof[c] = (short)n;
        if (base + k < 1024) s_nxt[base + k] = (unsigned short)c;
        int pos = s_bfscnt + base + k;
        if (pos < 1024){
          s_bfs[pos] = (unsigned short)c;
          s_o2b[c] = (unsigned short)pos;
        }
        k++;
      }
    }
    __syncthreads();
    if (tid == 0){ s_bfscnt += s_nextsz; s_cursz = (s_nextsz > 1024) ? 1024 : s_nextsz; }
    __syncthreads();
    if (tid < s_cursz) s_cur[tid] = s_nxt[tid];
    __syncthreads();
  }
  __syncthreads();

  int* BFSo = (int*)(ws + O_BFS);
  int* PARo = (int*)(ws + O_PAR);
  {
    int node = s_bfs[tid] & 1023;
    BFSo[b * 1024 + tid] = node;
    int p = s_parof[node];
    PARo[b * 1024 + tid] = (p < 0) ? -1 : (int)(s_o2b[p] & 1023);
  }
}

// ---------------- K4: X, delta, Bp, Cp ----------------
__global__ __launch_bounds__(256) void k_xdelta(float* __restrict__ ws)
{
  __shared__ float xs[256];
  int blk = blockIdx.x; int b = blk >> 10, i = blk & 1023; int df = threadIdx.x;
  const int* BFSo = (const int*)(ws + O_BFS);
  int node = BFSo[b * 1024 + i] & 1023;
  float rs = ws[O_RSEM + b * 1024 + node];
  float xv = ws[O_FEATS + ((size_t)(b * 1024 + node)) * 256 + df] + rs * ws[O_GPRIM + b * 256 + df];
  xs[df] = xv;
  ws[O_X + ((size_t)(b * 1024 + i)) * 256 + df] = xv;
  __syncthreads();
  {
    const float4* wrow = (const float4*)(ws + O_WDW + (size_t)df * 256);
    float z = ws[O_WDB + df];
    #pragma unroll 4
    for (int k = 0; k < 64; k++){
      float4 w = wrow[k];
      z += w.x * xs[4*k] + w.y * xs[4*k+1] + w.z * xs[4*k+2] + w.w * xs[4*k+3];
    }
    float sp = fmaxf(z, 0.f) + log1pf(expf(-fabsf(z)));
    ws[O_DELTA + ((size_t)(b * 1024 + i)) * 256 + df] = sp * (1.f + 2.f * rs);
  }
  if (df < 32){
    int s = df & 15;
    const float* W = ws + ((df < 16) ? O_BWO : O_CWO) + (size_t)s * 256;
    float a = ws[((df < 16) ? O_BBO : O_CBO) + s];
    for (int k = 0; k < 256; k++) a += W[k] * xs[k];
    ws[((df < 16) ? O_BP : O_CP) + (size_t)(b * 1024 + i) * 16 + s] = a;
  }
}

// ---------------- K5: tree scan, LDS history (one block per (b,f), 16 active lanes) ---
__global__ __launch_bounds__(64) void k_scan(float* __restrict__ ws)
{
  __shared__ float h[NP * DSTATE];   // 64 KB: h[pos][s]
  __shared__ float xs[NP];
  __shared__ float ds[NP];
  __shared__ int   par_s[NP];
  __shared__ int   bfs_s[NP];
  int blk = blockIdx.x; int b = blk >> 8, f = blk & 255;
  int lane = threadIdx.x;
  const int* PARo = (const int*)(ws + O_PAR);
  const int* BFSo = (const int*)(ws + O_BFS);
  for (int i = lane; i < NP; i += 64){
    xs[i] = ws[O_X     + ((size_t)(b * NP + i)) * DFEAT + f];
    ds[i] = ws[O_DELTA + ((size_t)(b * NP + i)) * DFEAT + f];
    par_s[i] = PARo[b * NP + i];
    bfs_s[i] = BFSo[b * NP + i] & 1023;
  }
  __syncthreads();
  if (lane < 16){
    int s = lane;
    float Aln = ws[O_AF + f * 16 + s];
    float Dv  = ws[O_DD + f];
    const float* Bp = ws + O_BP + (size_t)b * NP * DSTATE;
    const float* Cp = ws + O_CP + (size_t)b * NP * DSTATE;
    float* Yr = ws + O_YR + (size_t)b * NP * DFEAT;
    float bv = Bp[s], cv = Cp[s];
    for (int i = 0; i < NP; i++){
      float bv_n = 0.f, cv_n = 0.f;
      if (i + 1 < NP){ bv_n = Bp[(i + 1) * 16 + s]; cv_n = Cp[(i + 1) * 16 + s]; }
      int p = par_s[i];
      float d = ds[i], x = xs[i];
      float hp = (p >= 0) ? h[p * 16 + s] : 0.f;
      float hn = expf(d * Aln) * hp + d * bv * x;
      h[i * 16 + s] = hn;
      float t = hn * cv;
      t += __shfl_xor(t, 1); t += __shfl_xor(t, 2);
      t += __shfl_xor(t, 4); t += __shfl_xor(t, 8);
      if (s == 0) Yr[(size_t)bfs_s[i] * DFEAT + f] = t + Dv * x;
      bv = bv_n; cv = cv_n;
    }
  }
}

// ---------------- K6: out GEMM + LayerNorm -> bf16 or fp32 per sniffed dtype ---------
__global__ __launch_bounds__(256) void k_outln(const float* __restrict__ ws,
                                               void* __restrict__ out)
{
  __shared__ float yl[256];
  __shared__ float red[8];
  const int F = ((const int*)(ws + O_FLAG))[0];
  int blk = blockIdx.x; int b = blk >> 10, p = blk & 1023; int df = threadIdx.x;
  yl[df] = ws[O_YR + ((size_t)(b * 1024 + p)) * 256 + df];
  __syncthreads();
  const float4* wrow = (const float4*)(ws + O_OW + (size_t)df * 256);
  float a = ws[O_OB + df];
  #pragma unroll 4
  for (int k = 0; k < 64; k++){
    float4 w = wrow[k];
    a += w.x * yl[4*k] + w.y * yl[4*k+1] + w.z * yl[4*k+2] + w.w * yl[4*k+3];
  }
  int lane = df & 63, wid = df >> 6;
  float t = a;
  t += __shfl_xor(t, 1); t += __shfl_xor(t, 2);  t += __shfl_xor(t, 4);
  t += __shfl_xor(t, 8); t += __shfl_xor(t, 16); t += __shfl_xor(t, 32);
  if (lane == 0) red[wid] = t;
  __syncthreads();
  float mu = (red[0] + red[1] + red[2] + red[3]) * (1.f / 256.f);
  float dv = a - mu;
  float t2 = dv * dv;
  t2 += __shfl_xor(t2, 1); t2 += __shfl_xor(t2, 2);  t2 += __shfl_xor(t2, 4);
  t2 += __shfl_xor(t2, 8); t2 += __shfl_xor(t2, 16); t2 += __shfl_xor(t2, 32);
  if (lane == 0) red[4 + wid] = t2;
  __syncthreads();
  float var = (red[4] + red[5] + red[6] + red[7]) * (1.f / 256.f);
  float o = ws[O_LNG + df] * dv / sqrtf(var + 1e-5f) + ws[O_LNB + df];
  size_t idx = ((size_t)(b * 1024 + p)) * 256 + df;
  if (F) ((ushortb*)out)[idx] = f2bf(o);
  else   ((float*)out)[idx]   = o;
}

// ---------------- launch ----------------
extern "C" void kernel_launch(void* const* d_in, const int* in_sizes, int n_in,
                              void* d_out, int out_size, void* d_ws, size_t ws_size,
                              hipStream_t stream)
{
  (void)in_sizes; (void)n_in; (void)out_size; (void)ws_size;
  const void* img   = d_in[0];
  const void* lang  = d_in[1];
  const void* c1w   = d_in[2];
  const void* c1b   = d_in[3];
  const void* c2w   = d_in[4];
  const void* c2b   = d_in[5];
  const void* fcw   = d_in[6];
  const void* fcb   = d_in[7];
  const void* wgate = d_in[8];
  const void* wgp   = d_in[9];
  const void* alog  = d_in[10];
  const void* dvec  = d_in[11];
  const void* bw    = d_in[12];
  const void* bb    = d_in[13];
  const void* cw    = d_in[14];
  const void* cb    = d_in[15];
  const void* wdw   = d_in[16];
  const void* wdb   = d_in[17];
  const void* ow    = d_in[18];
  const void* ob    = d_in[19];
  const void* lng   = d_in[20];
  const void* lnb   = d_in[21];
  float* ws = (float*)d_ws;

  k_sniff<<<1, 256, 0, stream>>>(img, ws);
  k_convert<<<990, 256, 0, stream>>>(c1w, c1b, c2w, c2b, fcw, fcb, alog, dvec,
                                     bw, bb, cw, cb, wdw, wdb, ow, ob, lng, lnb, ws);
  k_init<<<2048, 256, 0, stream>>>(ws);
  k_patch<<<2048, 512, 0, stream>>>(img, ws, ws + O_FEATS);
  k_gmm<<<256, 256, 0, stream>>>(lang, wgate, wgp, ws);
  k_rsem<<<512, 256, 0, stream>>>(ws);
  k_struct<<<2, 1024, 0, stream>>>(ws);
  k_xdelta<<<2048, 256, 0, stream>>>(ws);
  k_scan<<<NB * DFEAT, 64, 0, stream>>>(ws);
  k_outln<<<2048, 256, 0, stream>>>(ws, d_out);
}

// Round 12
// 2362.929 us; speedup vs baseline: 1.3608x; 1.3608x over previous
//
#include <hip/hip_runtime.h>
#include <cstddef>
#include <cstdint>

// ---------------- constants ----------------
#define NB    2
#define NP    1024    // patches per image
#define DFEAT 256
#define DSTATE 16
#define NEDGE 1984    // grid edges: 31*63 + 31

typedef unsigned short ushortb;

// ---------------- helpers ----------------
__device__ __forceinline__ float bf2f(unsigned short u){
  union { unsigned int i; float f; } c; c.i = ((unsigned int)u) << 16; return c.f;
}
__device__ __forceinline__ unsigned short f2bf(float f){
  union { float f; unsigned int i; } c; c.f = f;
  unsigned int u = c.i;
  unsigned int r = (u + 0x7fffu + ((u >> 16) & 1u)) >> 16;
  return (unsigned short)r;
}
// dtype-generic input load: isbf ? bf16[i] : fp32[i]
__device__ __forceinline__ float ldin(const void* p, size_t i, int isbf){
  return isbf ? bf2f(((const ushortb*)p)[i]) : ((const float*)p)[i];
}
__device__ __forceinline__ float gelu_f(float x){
  return 0.5f * x * (1.0f + erff(x * 0.70710678118654752f));
}
__device__ __forceinline__ unsigned int f2sort(float f){
  union { float f; unsigned int i; } c; c.f = f;
  return (c.i & 0x80000000u) ? ~c.i : (c.i | 0x80000000u);
}

// ---------------- ws layout (float element offsets) ----------------
constexpr size_t AL(size_t x){ return (x + 63) & ~(size_t)63; }
constexpr size_t O_W1    = 0;                       // 1728  conv1 w fp32
constexpr size_t O_B1    = AL(O_W1 + 1728);         // 64
constexpr size_t O_W2    = AL(O_B1 + 64);           // 73728 conv2 w fp32, layout [g][ic][ocl][9]
constexpr size_t O_B2    = AL(O_W2 + 73728);        // 128
constexpr size_t O_FCW   = AL(O_B2 + 128);          // 32768 [df][128]
constexpr size_t O_FCB   = AL(O_FCW + 32768);       // 256
constexpr size_t O_WDW   = AL(O_FCB + 256);         // 65536 [df][256]
constexpr size_t O_WDB   = AL(O_WDW + 65536);       // 256
constexpr size_t O_BWO   = AL(O_WDB + 256);         // 4096 [s][256]
constexpr size_t O_BBO   = AL(O_BWO + 4096);        // 16
constexpr size_t O_CWO   = AL(O_BBO + 16);          // 4096
constexpr size_t O_CBO   = AL(O_CWO + 4096);        // 16
constexpr size_t O_OW    = AL(O_CBO + 16);          // 65536 [df][256]
constexpr size_t O_OB    = AL(O_OW + 65536);        // 256
constexpr size_t O_AF    = AL(O_OB + 256);          // 4096  A = -exp(A_log), [f][s]
constexpr size_t O_DD    = AL(O_AF + 4096);         // 256
constexpr size_t O_LNG   = AL(O_DD + 256);          // 256
constexpr size_t O_LNB   = AL(O_LNG + 256);         // 256
constexpr size_t O_FEATS = AL(O_LNB + 256);         // 2*1024*256
constexpr size_t O_GPROJ = AL(O_FEATS + (size_t)NB*NP*DFEAT); // 512
constexpr size_t O_GPRIM = AL(O_GPROJ + NB*DFEAT);  // 512
constexpr size_t O_RSEM  = AL(O_GPRIM + NB*DFEAT);  // 2048
constexpr size_t O_BFS   = AL(O_RSEM + NB*NP);      // 2048 (int)
constexpr size_t O_PAR   = AL(O_BFS + NB*NP);       // 2048 (int)
constexpr size_t O_X     = AL(O_PAR + NB*NP);       // 2*1024*256
constexpr size_t O_DELTA = AL(O_X + (size_t)NB*NP*DFEAT);
constexpr size_t O_BP    = AL(O_DELTA + (size_t)NB*NP*DFEAT); // 2*1024*16
constexpr size_t O_CP    = AL(O_BP + NB*NP*DSTATE);
constexpr size_t O_YR    = AL(O_CP + NB*NP*DSTATE); // 2*1024*256
constexpr size_t O_FLAG  = AL(O_YR + (size_t)NB*NP*DFEAT);    // 1 int: is-bf16 flag

// ---------------- K-1: sniff input dtype (bf16 vs fp32) from images buffer -----------
__global__ __launch_bounds__(256) void k_sniff(const void* img, float* ws)
{
  __shared__ int cnt;
  int tid = threadIdx.x;
  if (tid == 0) cnt = 0;
  __syncthreads();
  const ushortb* u = (const ushortb*)img;
  int local = 0;
  for (int k = 0; k < 16; k++){
    unsigned short v = u[tid * 16 + k];
    if (v == 0 || v == 0x8000u){ local++; continue; }
    float f = fabsf(bf2f(v));
    if (f >= 1e-8f && f <= 64.f) local++;    // plausible N(0,1) bf16
  }
  atomicAdd(&cnt, local);
  __syncthreads();
  if (tid == 0) ((int*)(ws + O_FLAG))[0] = (cnt >= 3900) ? 1 : 0;  // >=95% plausible
}

// ---------------- K0: convert weights -> fp32 + zero-init YR (fused, R12) ------------
__global__ void k_convert(const void* c1w, const void* c1b, const void* c2w,
                          const void* c2b, const void* fcw, const void* fcb,
                          const void* alog, const void* dvec,
                          const void* bw, const void* bb, const void* cw, const void* cb,
                          const void* wdw, const void* wdb,
                          const void* ow, const void* ob,
                          const void* lng, const void* lnb, float* ws)
{
  const int F = ((const int*)(ws + O_FLAG))[0];
  if (blockIdx.x >= 990){   // init branch: zero YR
    size_t i2 = (size_t)(blockIdx.x - 990) * 256 + threadIdx.x;
    if (i2 < (size_t)NB * NP * DFEAT) ws[O_YR + i2] = 0.f;
    return;
  }
  int i = blockIdx.x * 256 + threadIdx.x;
  if (i < 1728){ ws[O_W1 + i] = ldin(c1w, i, F); return; } i -= 1728;
  if (i < 64){ ws[O_B1 + i] = ldin(c1b, i, F); return; } i -= 64;
  if (i < 73728){
    // dst layout [g=0..15][ic=0..63][ocl=0..7][9]: i = ((g*64+ic)*8+ocl)*9 + t
    // oc = (g>>3)*64 + (g&7)*8 + ocl  (g = h*8 + w in k_patch)
    int g = i / 4608; int r = i - g * 4608;
    int ic = r / 72;  int r2 = r - ic * 72;
    int ocl = r2 / 9; int t = r2 - ocl * 9;
    int oc = (g >> 3) * 64 + (g & 7) * 8 + ocl;
    ws[O_W2 + i] = ldin(c2w, (size_t)(oc * 64 + ic) * 9 + t, F); return;
  } i -= 73728;
  if (i < 128){ ws[O_B2 + i] = ldin(c2b, i, F); return; } i -= 128;
  if (i < 32768){ ws[O_FCW + i] = ldin(fcw, i, F); return; } i -= 32768;
  if (i < 256){ ws[O_FCB + i] = ldin(fcb, i, F); return; } i -= 256;
  if (i < 65536){ ws[O_WDW + i] = ldin(wdw, i, F); return; } i -= 65536;
  if (i < 256){ ws[O_WDB + i] = ldin(wdb, i, F); return; } i -= 256;
  if (i < 4096){ ws[O_BWO + i] = ldin(bw, i, F); return; } i -= 4096;
  if (i < 16){ ws[O_BBO + i] = ldin(bb, i, F); return; } i -= 16;
  if (i < 4096){ ws[O_CWO + i] = ldin(cw, i, F); return; } i -= 4096;
  if (i < 16){ ws[O_CBO + i] = ldin(cb, i, F); return; } i -= 16;
  if (i < 65536){ ws[O_OW + i] = ldin(ow, i, F); return; } i -= 65536;
  if (i < 256){ ws[O_OB + i] = ldin(ob, i, F); return; } i -= 256;
  if (i < 4096){ ws[O_AF + i] = -expf(ldin(alog, i, F)); return; } i -= 4096;
  if (i < 256){ ws[O_DD + i] = ldin(dvec, i, F); return; } i -= 256;
  if (i < 256){ ws[O_LNG + i] = ldin(lng, i, F); return; } i -= 256;
  if (i < 256){ ws[O_LNB + i] = ldin(lnb, i, F); return; }
}

// ---------------- K1: per-patch conv1+gelu+conv2+gelu+pool+fc (R8 verbatim) ----------
// R11 post-mortem: any structure where conv2's acc is live during conv1 spills at the
// (512,4)-implied VGPR=64 (R6: 1.74 GB, R11: 351 MB scratch). R8's shape — conv1 fully
// before acc becomes live, lane=4px, wave=8oc, 72 wave-uniform weights per 288 FMAs —
// is the measured optimum (1585 us); locked here.
__global__ __launch_bounds__(512, 4) void k_patch(const void* __restrict__ img,
                                                  const float* __restrict__ ws,
                                                  float* __restrict__ feats)
{
  __shared__ float sm[64 * 256];  // 64KB: h1 [64 ic][256 px]
  __shared__ float timg[768];     // 3KB input tile [3 c][256 px]
  __shared__ float pool[128];     // pooled sums per oc
  __shared__ float pm[128];       // pooled mean
  const int F = ((const int*)(ws + O_FLAG))[0];
  const float* W1 = ws + O_W1;  const float* B1 = ws + O_B1;
  const float* W2 = ws + O_W2;  const float* B2 = ws + O_B2;
  const float* FCW = ws + O_FCW; const float* FCB = ws + O_FCB;

  int blk = blockIdx.x; int b = blk >> 10; int pidx = blk & 1023;
  int ph = pidx >> 5, pw = pidx & 31;
  int tid = threadIdx.x;

  // stage input tile (16x16x3) into LDS
  if (tid < 256){
    int y = tid >> 4, x = tid & 15;
    #pragma unroll
    for (int c = 0; c < 3; c++)
      timg[c * 256 + tid] =
        ldin(img, (((size_t)b * 3 + c) * 512 + (ph * 16 + y)) * 512 + (pw * 16 + x), F);
  }
  __syncthreads();

  // conv1 + gelu -> sm: thread = (pixel p, oc-group og of 32)
  {
    int p = tid & 255, og = tid >> 8;
    int ii = p >> 4, jj = p & 15;
    float pin[27];
    #pragma unroll
    for (int c = 0; c < 3; c++)
      #pragma unroll
      for (int dy = 0; dy < 3; dy++)
        #pragma unroll
        for (int dx = 0; dx < 3; dx++){
          int y = ii + dy - 1, x = jj + dx - 1;
          bool ok = (y >= 0 && y < 16 && x >= 0 && x < 16);
          pin[c * 9 + dy * 3 + dx] = ok ? timg[c * 256 + y * 16 + x] : 0.f;
        }
    for (int o = 0; o < 32; o++){
      int oc = og * 32 + o;
      float a = B1[oc];
      #pragma unroll
      for (int t = 0; t < 27; t++) a += W1[oc * 27 + t] * pin[t];
      sm[oc * 256 + p] = gelu_f(a);
    }
  }
  __syncthreads();

  // conv2: wave w (0..7) x half h (0..1) -> 8 oc; lane = 4 consecutive px in a row
  int wv = tid >> 6, ln = tid & 63;
  int row = ln >> 2, cg = ln & 3;
  int c0 = cg * 4;   // first pixel col of this lane's group

  for (int h = 0; h < 2; h++){
    int oc0 = h * 64 + wv * 8;
    float acc[4][8];
    #pragma unroll
    for (int o = 0; o < 8; o++){
      float bz = B2[oc0 + o];
      #pragma unroll
      for (int j = 0; j < 4; j++) acc[j][o] = bz;
    }
    const float* wg = W2 + ((size_t)(h * 8 + wv)) * 4608;   // [ic][ocl][9]
    for (int ic = 0; ic < 64; ic++){
      float win[3][6];
      #pragma unroll
      for (int r = 0; r < 3; r++){
        int y = row - 1 + r;
        bool yok = (y >= 0 && y < 16);
        #pragma unroll
        for (int cc = 0; cc < 6; cc++){
          int x = c0 - 1 + cc;
          win[r][cc] = (yok && x >= 0 && x < 16) ? sm[ic * 256 + y * 16 + x] : 0.f;
        }
      }
      const float* wp = wg + (size_t)ic * 72;   // 72 contiguous wave-uniform floats
      #pragma unroll
      for (int o = 0; o < 8; o++){
        #pragma unroll
        for (int t9 = 0; t9 < 9; t9++){
          int dy = t9 / 3, dx = t9 - dy * 3;
          float wvv = wp[o * 9 + t9];
          #pragma unroll
          for (int j = 0; j < 4; j++)
            acc[j][o] += wvv * win[dy][j + dx];
        }
      }
    }
    // gelu + pool: lane sums its 4 px, wave-reduce over 64 lanes (256 px total)
    #pragma unroll
    for (int o = 0; o < 8; o++){
      float g = gelu_f(acc[0][o]) + gelu_f(acc[1][o]) + gelu_f(acc[2][o]) + gelu_f(acc[3][o]);
      g += __shfl_xor(g, 1);  g += __shfl_xor(g, 2);  g += __shfl_xor(g, 4);
      g += __shfl_xor(g, 8);  g += __shfl_xor(g, 16); g += __shfl_xor(g, 32);
      if (ln == 0) pool[oc0 + o] = g;   // waves own disjoint oc, no merge needed
    }
  }
  __syncthreads();
  if (tid < 128) pm[tid] = pool[tid] * (1.f / 256.f);
  __syncthreads();

  // fc 128 -> 256 (threads 0..255)
  if (tid < 256){
    int df = tid;
    float s = FCB[df];
    const float* wrow = FCW + (size_t)df * 128;
    #pragma unroll
    for (int k = 0; k < 128; k += 4)
      s += wrow[k] * pm[k] + wrow[k + 1] * pm[k + 1]
         + wrow[k + 2] * pm[k + 2] + wrow[k + 3] * pm[k + 3];
    feats[((size_t)(b * 1024 + pidx)) * 256 + df] = s;
  }
}

// ---------------- K2: g_proj / g_prime, wave-per-row coalesced ----------------------
__global__ __launch_bounds__(256) void k_gmm(const void* __restrict__ lang,
                                             const void* __restrict__ wgate,
                                             const void* __restrict__ wgp,
                                             float* __restrict__ ws)
{
  const int F = ((const int*)(ws + O_FLAG))[0];
  int row = blockIdx.x * 4 + (threadIdx.x >> 6);
  int lane = threadIdx.x & 63;
  int mat = row >> 9;
  int b   = (row >> 8) & 1;
  int df  = row & 255;
  const void* W = mat ? wgp : wgate;
  float s = 0.f;
  for (int k = lane; k < 896; k += 64)
    s += ldin(lang, (size_t)b * 896 + k, F) * ldin(W, (size_t)df * 896 + k, F);
  s += __shfl_xor(s, 1);  s += __shfl_xor(s, 2);  s += __shfl_xor(s, 4);
  s += __shfl_xor(s, 8);  s += __shfl_xor(s, 16); s += __shfl_xor(s, 32);
  if (lane == 0) ws[(mat ? O_GPRIM : O_GPROJ) + b * 256 + df] = s;
}

// ---------------- K3: structure (rsem fused + Boruvka MST + adjacency + level BFS) ---
__device__ __forceinline__ void edge_uv(int e, int& u, int& v){
  if (e < 1953){
    int i = e / 63; int k = e - i * 63;
    if (k < 62){ int j = k >> 1; u = i * 32 + j; v = (k & 1) ? u + 32 : u + 1; }
    else { u = i * 32 + 31; v = u + 32; }
  } else { u = 31 * 32 + (e - 1953); v = u + 1; }
}

__global__ __launch_bounds__(1024) void k_struct(float* __restrict__ ws)
{
  __shared__ float s_ninv[1024];
  __shared__ float s_w[NEDGE];
  __shared__ float s_r[1024];
  __shared__ int   s_comp[1024];
  __shared__ int   s_link[1024];
  __shared__ int   s_link2[1024];
  __shared__ unsigned long long s_best[1024];
  __shared__ unsigned char  s_mst[NEDGE];
  __shared__ unsigned short s_adj[1024 * 4];
  __shared__ unsigned char  s_deg[1024];
  __shared__ unsigned short s_bfs[1024];
  __shared__ short          s_parof[1024];
  __shared__ unsigned short s_o2b[1024];
  __shared__ unsigned short s_cur[1024];
  __shared__ unsigned short s_nxt[1024];
  __shared__ unsigned short s_off[1025];
  __shared__ unsigned long long s_rootkey;
  __shared__ int s_ncomp, s_cursz, s_bfscnt, s_nextsz;

  int b = blockIdx.x; int tid = threadIdx.x;
  const float* feats = ws + O_FEATS + (size_t)b * NP * DFEAT;

  // norms + fused r_sem (one pass over the thread's feats row) + defensive init
  {
    const float4* f4 = (const float4*)(feats + (size_t)tid * 256);
    const float4* g4 = (const float4*)(ws + O_GPROJ + b * 256);
    float d = 0.f, gdot = 0.f;
    for (int k = 0; k < 64; k++){
      float4 q = f4[k]; float4 g = g4[k];
      d += q.x*q.x + q.y*q.y + q.z*q.z + q.w*q.w;
      gdot += q.x*g.x + q.y*g.y + q.z*g.z + q.w*g.w;
    }
    s_ninv[tid] = 1.f / fmaxf(sqrtf(d), 1e-12f);
    float r = 1.f / (1.f + expf(-gdot * (1.f / 16.f)));
    s_r[tid] = r;
    ws[O_RSEM + b * NP + tid] = r;      // k_xdelta consumes this
    s_comp[tid] = tid;
    s_deg[tid] = 0;
    s_bfs[tid] = (unsigned short)tid;
    s_o2b[tid] = (unsigned short)tid;
    s_parof[tid] = -1;
  }
  for (int e = tid; e < NEDGE; e += 1024) s_mst[e] = 0;
  __syncthreads();

  // edge weights
  for (int e = tid; e < NEDGE; e += 1024){
    int u, v; edge_uv(e, u, v);
    const float4* fu = (const float4*)(feats + (size_t)u * 256);
    const float4* fv = (const float4*)(feats + (size_t)v * 256);
    float d = 0.f;
    for (int k = 0; k < 64; k++){ float4 a = fu[k], c = fv[k]; d += a.x*c.x + a.y*c.y + a.z*c.z + a.w*c.w; }
    float cosv = d * s_ninv[u] * s_ninv[v];
    s_w[e] = (1.f - s_r[u]) * (1.f - s_r[v]) * (-cosv) + 1e-6f;
  }
  __syncthreads();

  // Boruvka rounds
  for (int round = 0; round < 12; round++){
    s_best[tid] = ~0ull;
    __syncthreads();
    for (int e = tid; e < NEDGE; e += 1024){
      int u, v; edge_uv(e, u, v);
      int cu = s_comp[u], cv = s_comp[v];
      if (cu != cv){
        unsigned long long key = (((unsigned long long)f2sort(s_w[e])) << 32) | (unsigned int)e;
        atomicMin(&s_best[cu], key);
        atomicMin(&s_best[cv], key);
      }
    }
    __syncthreads();
    int l = tid;
    if (s_comp[tid] == tid && s_best[tid] != ~0ull){
      int e = (int)(s_best[tid] & 0xffffffffu);
      int u, v; edge_uv(e, u, v);
      s_mst[e] = 1;
      int cu = s_comp[u], cv = s_comp[v];
      l = (cu == tid) ? cv : cu;
    }
    s_link[tid] = l;
    __syncthreads();
    if (l != tid && s_link[l] == tid && tid < l) s_link[tid] = tid; // break 2-cycles
    __syncthreads();
    for (int it = 0; it < 10; it++){      // pointer jumping (double-buffered)
      int x = s_link[tid]; s_link2[tid] = s_link[x];
      __syncthreads();
      s_link[tid] = s_link2[tid];
      __syncthreads();
    }
    s_comp[tid] = s_link[s_comp[tid]];
    if (tid == 0) s_ncomp = 0;
    __syncthreads();
    if (s_comp[tid] == tid) atomicAdd(&s_ncomp, 1);
    __syncthreads();
    if (s_ncomp == 1) break;
    __syncthreads();
  }
  __syncthreads();

  // weight-ordered adjacency (== Kruskal insertion order for unique MST)
  {
    int v = tid; int i = v >> 5, j = v & 31;
    float wloc[4]; int nloc[4]; int d = 0;
    if (j > 0){ int e = (i < 31) ? (i * 63 + 2 * (j - 1)) : (1953 + (j - 1));
      if (s_mst[e]){ wloc[d] = s_w[e]; nloc[d] = v - 1; d++; } }
    if (j < 31){ int e = (i < 31) ? (i * 63 + 2 * j) : (1953 + j);
      if (s_mst[e]){ wloc[d] = s_w[e]; nloc[d] = v + 1; d++; } }
    if (i > 0){ int e = (i - 1) * 63 + ((j < 31) ? (2 * j + 1) : 62);
      if (s_mst[e]){ wloc[d] = s_w[e]; nloc[d] = v - 32; d++; } }
    if (i < 31){ int e = i * 63 + ((j < 31) ? (2 * j + 1) : 62);
      if (s_mst[e]){ wloc[d] = s_w[e]; nloc[d] = v + 32; d++; } }
    for (int a = 1; a < d; a++){
      float wv = wloc[a]; int nv = nloc[a]; int c = a - 1;
      while (c >= 0 && wloc[c] > wv){ wloc[c+1] = wloc[c]; nloc[c+1] = nloc[c]; c--; }
      wloc[c+1] = wv; nloc[c+1] = nv;
    }
    s_deg[v] = (unsigned char)d;
    for (int a = 0; a < d; a++) s_adj[v * 4 + a] = (unsigned short)nloc[a];
  }
  // root = argmax r (first index on ties)
  if (tid == 0) s_rootkey = 0ull;
  __syncthreads();
  {
    unsigned long long key = (((unsigned long long)f2sort(s_r[tid])) << 32) | (unsigned int)(1023 - tid);
    atomicMax(&s_rootkey, key);
  }
  __syncthreads();
  int root = 1023 - (int)(s_rootkey & 0xffffffffu);

  // level-parallel tree BFS
  if (tid == 0){
    s_bfs[0] = (unsigned short)root; s_o2b[root] = 0; s_parof[root] = -1;
    s_cur[0] = (unsigned short)root; s_cursz = 1; s_bfscnt = 1;
  }
  __syncthreads();
  for (int lev = 0; lev < 1024; lev++){
    int csz = s_cursz;
    if (csz <= 0) break;
    // wave-parallel exclusive scan of child counts
    if (tid < 64){
      int runbase = 0;
      for (int t0 = 0; t0 < csz; t0 += 64){
        int t = t0 + tid;
        int cnt = 0;
        if (t < csz){
          int n = s_cur[t];
          cnt = (int)s_deg[n] - (s_parof[n] >= 0 ? 1 : 0);
        }
        int v = cnt;
        #pragma unroll
        for (int off = 1; off < 64; off <<= 1){
          int u2 = __shfl_up(v, off);
          if (tid >= off) v += u2;
        }
        if (t < csz) s_off[t] = (unsigned short)(runbase + v - cnt);
        runbase += __shfl(v, 63);
      }
      if (tid == 0) s_nextsz = runbase;
    }
    __syncthreads();
    if (tid < csz){
      int n = s_cur[tid]; int base = s_off[tid]; int k = 0;
      int pn = s_parof[n]; int dg = s_deg[n];
      for (int a = 0; a < dg; a++){
        int c = s_adj[n * 4 + a];
        if (c == pn) continue;
        s_parof[c] = (short)n;
        if (base + k < 1024) s_nxt[base + k] = (unsigned short)c;
        int pos = s_bfscnt + base + k;
        if (pos < 1024){
          s_bfs[pos] = (unsigned short)c;
          s_o2b[c] = (unsigned short)pos;
        }
        k++;
      }
    }
    __syncthreads();
    if (tid == 0){ s_bfscnt += s_nextsz; s_cursz = (s_nextsz > 1024) ? 1024 : s_nextsz; }
    __syncthreads();
    if (tid < s_cursz) s_cur[tid] = s_nxt[tid];
    __syncthreads();
  }
  __syncthreads();

  int* BFSo = (int*)(ws + O_BFS);
  int* PARo = (int*)(ws + O_PAR);
  {
    int node = s_bfs[tid] & 1023;
    BFSo[b * 1024 + tid] = node;
    int p = s_parof[node];
    PARo[b * 1024 + tid] = (p < 0) ? -1 : (int)(s_o2b[p] & 1023);
  }
}

// ---------------- K4: X, delta, Bp, Cp ----------------
__global__ __launch_bounds__(256) void k_xdelta(float* __restrict__ ws)
{
  __shared__ float xs[256];
  int blk = blockIdx.x; int b = blk >> 10, i = blk & 1023; int df = threadIdx.x;
  const int* BFSo = (const int*)(ws + O_BFS);
  int node = BFSo[b * 1024 + i] & 1023;
  float rs = ws[O_RSEM + b * 1024 + node];
  float xv = ws[O_FEATS + ((size_t)(b * 1024 + node)) * 256 + df] + rs * ws[O_GPRIM + b * 256 + df];
  xs[df] = xv;
  ws[O_X + ((size_t)(b * 1024 + i)) * 256 + df] = xv;
  __syncthreads();
  {
    const float4* wrow = (const float4*)(ws + O_WDW + (size_t)df * 256);
    float z = ws[O_WDB + df];
    #pragma unroll 4
    for (int k = 0; k < 64; k++){
      float4 w = wrow[k];
      z += w.x * xs[4*k] + w.y * xs[4*k+1] + w.z * xs[4*k+2] + w.w * xs[4*k+3];
    }
    float sp = fmaxf(z, 0.f) + log1pf(expf(-fabsf(z)));
    ws[O_DELTA + ((size_t)(b * 1024 + i)) * 256 + df] = sp * (1.f + 2.f * rs);
  }
  if (df < 32){
    int s = df & 15;
    const float* W = ws + ((df < 16) ? O_BWO : O_CWO) + (size_t)s * 256;
    float a = ws[((df < 16) ? O_BBO : O_CBO) + s];
    for (int k = 0; k < 256; k++) a += W[k] * xs[k];
    ws[((df < 16) ? O_BP : O_CP) + (size_t)(b * 1024 + i) * 16 + s] = a;
  }
}

// ---------------- K5: tree scan, LDS history; 4-deep B/C prefetch (R12) --------------
__global__ __launch_bounds__(64) void k_scan(float* __restrict__ ws)
{
  __shared__ float h[NP * DSTATE];   // 64 KB: h[pos][s]
  __shared__ float xs[NP];
  __shared__ float ds[NP];
  __shared__ int   par_s[NP];
  __shared__ int   bfs_s[NP];
  int blk = blockIdx.x; int b = blk >> 8, f = blk & 255;
  int lane = threadIdx.x;
  const int* PARo = (const int*)(ws + O_PAR);
  const int* BFSo = (const int*)(ws + O_BFS);
  for (int i = lane; i < NP; i += 64){
    xs[i] = ws[O_X     + ((size_t)(b * NP + i)) * DFEAT + f];
    ds[i] = ws[O_DELTA + ((size_t)(b * NP + i)) * DFEAT + f];
    par_s[i] = PARo[b * NP + i];
    bfs_s[i] = BFSo[b * NP + i] & 1023;
  }
  __syncthreads();
  if (lane < 16){
    int s = lane;
    float Aln = ws[O_AF + f * 16 + s];
    float Dv  = ws[O_DD + f];
    const float* Bp = ws + O_BP + (size_t)b * NP * DSTATE;
    const float* Cp = ws + O_CP + (size_t)b * NP * DSTATE;
    float* Yr = ws + O_YR + (size_t)b * NP * DFEAT;
    // 4-deep register ring: prefetch distance ~4 loop bodies > L2 latency (m126)
    float bvr[4], cvr[4];
    #pragma unroll
    for (int k = 0; k < 4; k++){ bvr[k] = Bp[k * 16 + s]; cvr[k] = Cp[k * 16 + s]; }
    #pragma unroll 4
    for (int i = 0; i < NP; i++){
      float bv = bvr[i & 3], cv = cvr[i & 3];
      int ip = i + 4;
      if (ip < NP){ bvr[i & 3] = Bp[ip * 16 + s]; cvr[i & 3] = Cp[ip * 16 + s]; }
      int p = par_s[i];
      float d = ds[i], x = xs[i];
      float hp = (p >= 0) ? h[p * 16 + s] : 0.f;
      float hn = expf(d * Aln) * hp + d * bv * x;
      h[i * 16 + s] = hn;
      float t = hn * cv;
      t += __shfl_xor(t, 1); t += __shfl_xor(t, 2);
      t += __shfl_xor(t, 4); t += __shfl_xor(t, 8);
      if (s == 0) Yr[(size_t)bfs_s[i] * DFEAT + f] = t + Dv * x;
    }
  }
}

// ---------------- K6: out GEMM + LayerNorm -> bf16 or fp32 per sniffed dtype ---------
__global__ __launch_bounds__(256) void k_outln(const float* __restrict__ ws,
                                               void* __restrict__ out)
{
  __shared__ float yl[256];
  __shared__ float red[8];
  const int F = ((const int*)(ws + O_FLAG))[0];
  int blk = blockIdx.x; int b = blk >> 10, p = blk & 1023; int df = threadIdx.x;
  yl[df] = ws[O_YR + ((size_t)(b * 1024 + p)) * 256 + df];
  __syncthreads();
  const float4* wrow = (const float4*)(ws + O_OW + (size_t)df * 256);
  float a = ws[O_OB + df];
  #pragma unroll 4
  for (int k = 0; k < 64; k++){
    float4 w = wrow[k];
    a += w.x * yl[4*k] + w.y * yl[4*k+1] + w.z * yl[4*k+2] + w.w * yl[4*k+3];
  }
  int lane = df & 63, wid = df >> 6;
  float t = a;
  t += __shfl_xor(t, 1); t += __shfl_xor(t, 2);  t += __shfl_xor(t, 4);
  t += __shfl_xor(t, 8); t += __shfl_xor(t, 16); t += __shfl_xor(t, 32);
  if (lane == 0) red[wid] = t;
  __syncthreads();
  float mu = (red[0] + red[1] + red[2] + red[3]) * (1.f / 256.f);
  float dv = a - mu;
  float t2 = dv * dv;
  t2 += __shfl_xor(t2, 1); t2 += __shfl_xor(t2, 2);  t2 += __shfl_xor(t2, 4);
  t2 += __shfl_xor(t2, 8); t2 += __shfl_xor(t2, 16); t2 += __shfl_xor(t2, 32);
  if (lane == 0) red[4 + wid] = t2;
  __syncthreads();
  float var = (red[4] + red[5] + red[6] + red[7]) * (1.f / 256.f);
  float o = ws[O_LNG + df] * dv / sqrtf(var + 1e-5f) + ws[O_LNB + df];
  size_t idx = ((size_t)(b * 1024 + p)) * 256 + df;
  if (F) ((ushortb*)out)[idx] = f2bf(o);
  else   ((float*)out)[idx]   = o;
}

// ---------------- launch ----------------
extern "C" void kernel_launch(void* const* d_in, const int* in_sizes, int n_in,
                              void* d_out, int out_size, void* d_ws, size_t ws_size,
                              hipStream_t stream)
{
  (void)in_sizes; (void)n_in; (void)out_size; (void)ws_size;
  const void* img   = d_in[0];
  const void* lang  = d_in[1];
  const void* c1w   = d_in[2];
  const void* c1b   = d_in[3];
  const void* c2w   = d_in[4];
  const void* c2b   = d_in[5];
  const void* fcw   = d_in[6];
  const void* fcb   = d_in[7];
  const void* wgate = d_in[8];
  const void* wgp   = d_in[9];
  const void* alog  = d_in[10];
  const void* dvec  = d_in[11];
  const void* bw    = d_in[12];
  const void* bb    = d_in[13];
  const void* cw    = d_in[14];
  const void* cb    = d_in[15];
  const void* wdw   = d_in[16];
  const void* wdb   = d_in[17];
  const void* ow    = d_in[18];
  const void* ob    = d_in[19];
  const void* lng   = d_in[20];
  const void* lnb   = d_in[21];
  float* ws = (float*)d_ws;

  k_sniff<<<1, 256, 0, stream>>>(img, ws);
  k_convert<<<990 + 2048, 256, 0, stream>>>(c1w, c1b, c2w, c2b, fcw, fcb, alog, dvec,
                                            bw, bb, cw, cb, wdw, wdb, ow, ob, lng, lnb, ws);
  k_patch<<<2048, 512, 0, stream>>>(img, ws, ws + O_FEATS);
  k_gmm<<<256, 256, 0, stream>>>(lang, wgate, wgp, ws);
  k_struct<<<2, 1024, 0, stream>>>(ws);
  k_xdelta<<<2048, 256, 0, stream>>>(ws);
  k_scan<<<NB * DFEAT, 64, 0, stream>>>(ws);
  k_outln<<<2048, 256, 0, stream>>>(ws, d_out);
}

// Round 13
// 2279.483 us; speedup vs baseline: 1.4107x; 1.0366x over previous
//
#include <hip/hip_runtime.h>
#include <cstddef>
#include <cstdint>

// ---------------- constants ----------------
#define NB    2
#define NP    1024    // patches per image
#define DFEAT 256
#define DSTATE 16
#define NEDGE 1984    // grid edges: 31*63 + 31

typedef unsigned short ushortb;

// ---------------- helpers ----------------
__device__ __forceinline__ float bf2f(unsigned short u){
  union { unsigned int i; float f; } c; c.i = ((unsigned int)u) << 16; return c.f;
}
__device__ __forceinline__ unsigned short f2bf(float f){
  union { float f; unsigned int i; } c; c.f = f;
  unsigned int u = c.i;
  unsigned int r = (u + 0x7fffu + ((u >> 16) & 1u)) >> 16;
  return (unsigned short)r;
}
// dtype-generic input load: isbf ? bf16[i] : fp32[i]
__device__ __forceinline__ float ldin(const void* p, size_t i, int isbf){
  return isbf ? bf2f(((const ushortb*)p)[i]) : ((const float*)p)[i];
}
__device__ __forceinline__ float gelu_f(float x){
  return 0.5f * x * (1.0f + erff(x * 0.70710678118654752f));
}
__device__ __forceinline__ unsigned int f2sort(float f){
  union { float f; unsigned int i; } c; c.f = f;
  return (c.i & 0x80000000u) ? ~c.i : (c.i | 0x80000000u);
}

// ---------------- ws layout (float element offsets) ----------------
constexpr size_t AL(size_t x){ return (x + 63) & ~(size_t)63; }
constexpr size_t O_W1    = 0;                       // 1728  conv1 w fp32
constexpr size_t O_B1    = AL(O_W1 + 1728);         // 64
constexpr size_t O_W2    = AL(O_B1 + 64);           // 73728 conv2 w fp32, layout [g][ic][ocl][9]
constexpr size_t O_B2    = AL(O_W2 + 73728);        // 128
constexpr size_t O_FCW   = AL(O_B2 + 128);          // 32768 [df][128]
constexpr size_t O_FCB   = AL(O_FCW + 32768);       // 256
constexpr size_t O_WDW   = AL(O_FCB + 256);         // 65536 TRANSPOSED [k][df]
constexpr size_t O_WDB   = AL(O_WDW + 65536);       // 256
constexpr size_t O_BWO   = AL(O_WDB + 256);         // 4096 TRANSPOSED [k][s]
constexpr size_t O_BBO   = AL(O_BWO + 4096);        // 16
constexpr size_t O_CWO   = AL(O_BBO + 16);          // 4096 TRANSPOSED [k][s]
constexpr size_t O_CBO   = AL(O_CWO + 4096);        // 16
constexpr size_t O_OW    = AL(O_CBO + 16);          // 65536 TRANSPOSED [k][df]
constexpr size_t O_OB    = AL(O_OW + 65536);        // 256
constexpr size_t O_AF    = AL(O_OB + 256);          // 4096  A = -exp(A_log), [f][s]
constexpr size_t O_DD    = AL(O_AF + 4096);         // 256
constexpr size_t O_LNG   = AL(O_DD + 256);          // 256
constexpr size_t O_LNB   = AL(O_LNG + 256);         // 256
constexpr size_t O_FEATS = AL(O_LNB + 256);         // 2*1024*256
constexpr size_t O_GPROJ = AL(O_FEATS + (size_t)NB*NP*DFEAT); // 512
constexpr size_t O_GPRIM = AL(O_GPROJ + NB*DFEAT);  // 512
constexpr size_t O_RSEM  = AL(O_GPRIM + NB*DFEAT);  // 2048
constexpr size_t O_BFS   = AL(O_RSEM + NB*NP);      // 2048 (int)
constexpr size_t O_PAR   = AL(O_BFS + NB*NP);       // 2048 (int)
constexpr size_t O_X     = AL(O_PAR + NB*NP);       // 2*1024*256
constexpr size_t O_DELTA = AL(O_X + (size_t)NB*NP*DFEAT);
constexpr size_t O_BP    = AL(O_DELTA + (size_t)NB*NP*DFEAT); // 2*1024*16
constexpr size_t O_CP    = AL(O_BP + NB*NP*DSTATE);
constexpr size_t O_YR    = AL(O_CP + NB*NP*DSTATE); // 2*1024*256
constexpr size_t O_FLAG  = AL(O_YR + (size_t)NB*NP*DFEAT);    // 1 int: is-bf16 flag

// ---------------- K-1: sniff input dtype (bf16 vs fp32) from images buffer -----------
__global__ __launch_bounds__(256) void k_sniff(const void* img, float* ws)
{
  __shared__ int cnt;
  int tid = threadIdx.x;
  if (tid == 0) cnt = 0;
  __syncthreads();
  const ushortb* u = (const ushortb*)img;
  int local = 0;
  for (int k = 0; k < 16; k++){
    unsigned short v = u[tid * 16 + k];
    if (v == 0 || v == 0x8000u){ local++; continue; }
    float f = fabsf(bf2f(v));
    if (f >= 1e-8f && f <= 64.f) local++;    // plausible N(0,1) bf16
  }
  atomicAdd(&cnt, local);
  __syncthreads();
  if (tid == 0) ((int*)(ws + O_FLAG))[0] = (cnt >= 3900) ? 1 : 0;  // >=95% plausible
}

// ---------------- K0: convert weights -> fp32 + zero-init YR (fused) ------------
// R13: WDW/OW stored transposed [k][df], B_w/C_w transposed [k][s] so the consumer
// dot loops are k-major: one coalesced lane-consecutive load + LDS broadcast per k
// (was row-per-thread = 64 cache lines per wave instruction).
__global__ void k_convert(const void* c1w, const void* c1b, const void* c2w,
                          const void* c2b, const void* fcw, const void* fcb,
                          const void* alog, const void* dvec,
                          const void* bw, const void* bb, const void* cw, const void* cb,
                          const void* wdw, const void* wdb,
                          const void* ow, const void* ob,
                          const void* lng, const void* lnb, float* ws)
{
  const int F = ((const int*)(ws + O_FLAG))[0];
  if (blockIdx.x >= 990){   // init branch: zero YR
    size_t i2 = (size_t)(blockIdx.x - 990) * 256 + threadIdx.x;
    if (i2 < (size_t)NB * NP * DFEAT) ws[O_YR + i2] = 0.f;
    return;
  }
  int i = blockIdx.x * 256 + threadIdx.x;
  if (i < 1728){ ws[O_W1 + i] = ldin(c1w, i, F); return; } i -= 1728;
  if (i < 64){ ws[O_B1 + i] = ldin(c1b, i, F); return; } i -= 64;
  if (i < 73728){
    // dst layout [g=0..15][ic=0..63][ocl=0..7][9]: i = ((g*64+ic)*8+ocl)*9 + t
    int g = i / 4608; int r = i - g * 4608;
    int ic = r / 72;  int r2 = r - ic * 72;
    int ocl = r2 / 9; int t = r2 - ocl * 9;
    int oc = (g >> 3) * 64 + (g & 7) * 8 + ocl;
    ws[O_W2 + i] = ldin(c2w, (size_t)(oc * 64 + ic) * 9 + t, F); return;
  } i -= 73728;
  if (i < 128){ ws[O_B2 + i] = ldin(c2b, i, F); return; } i -= 128;
  if (i < 32768){ ws[O_FCW + i] = ldin(fcw, i, F); return; } i -= 32768;
  if (i < 256){ ws[O_FCB + i] = ldin(fcb, i, F); return; } i -= 256;
  if (i < 65536){  // WDW transposed: dst[k*256+df] = src[df*256+k]
    int k = i >> 8, df = i & 255;
    ws[O_WDW + i] = ldin(wdw, (size_t)df * 256 + k, F); return;
  } i -= 65536;
  if (i < 256){ ws[O_WDB + i] = ldin(wdb, i, F); return; } i -= 256;
  if (i < 4096){   // B_w transposed: dst[k*16+s] = src[s*256+k]
    int k = i >> 4, s = i & 15;
    ws[O_BWO + i] = ldin(bw, (size_t)s * 256 + k, F); return;
  } i -= 4096;
  if (i < 16){ ws[O_BBO + i] = ldin(bb, i, F); return; } i -= 16;
  if (i < 4096){   // C_w transposed
    int k = i >> 4, s = i & 15;
    ws[O_CWO + i] = ldin(cw, (size_t)s * 256 + k, F); return;
  } i -= 4096;
  if (i < 16){ ws[O_CBO + i] = ldin(cb, i, F); return; } i -= 16;
  if (i < 65536){  // out_w transposed: dst[k*256+df] = src[df*256+k]
    int k = i >> 8, df = i & 255;
    ws[O_OW + i] = ldin(ow, (size_t)df * 256 + k, F); return;
  } i -= 65536;
  if (i < 256){ ws[O_OB + i] = ldin(ob, i, F); return; } i -= 256;
  if (i < 4096){ ws[O_AF + i] = -expf(ldin(alog, i, F)); return; } i -= 4096;
  if (i < 256){ ws[O_DD + i] = ldin(dvec, i, F); return; } i -= 256;
  if (i < 256){ ws[O_LNG + i] = ldin(lng, i, F); return; } i -= 256;
  if (i < 256){ ws[O_LNB + i] = ldin(lnb, i, F); return; }
}

// ---------------- K1: per-patch conv1+gelu+conv2+gelu+pool+fc (R8 verbatim) ----------
__global__ __launch_bounds__(512, 4) void k_patch(const void* __restrict__ img,
                                                  const float* __restrict__ ws,
                                                  float* __restrict__ feats)
{
  __shared__ float sm[64 * 256];  // 64KB: h1 [64 ic][256 px]
  __shared__ float timg[768];     // 3KB input tile [3 c][256 px]
  __shared__ float pool[128];     // pooled sums per oc
  __shared__ float pm[128];       // pooled mean
  const int F = ((const int*)(ws + O_FLAG))[0];
  const float* W1 = ws + O_W1;  const float* B1 = ws + O_B1;
  const float* W2 = ws + O_W2;  const float* B2 = ws + O_B2;
  const float* FCW = ws + O_FCW; const float* FCB = ws + O_FCB;

  int blk = blockIdx.x; int b = blk >> 10; int pidx = blk & 1023;
  int ph = pidx >> 5, pw = pidx & 31;
  int tid = threadIdx.x;

  // stage input tile (16x16x3) into LDS
  if (tid < 256){
    int y = tid >> 4, x = tid & 15;
    #pragma unroll
    for (int c = 0; c < 3; c++)
      timg[c * 256 + tid] =
        ldin(img, (((size_t)b * 3 + c) * 512 + (ph * 16 + y)) * 512 + (pw * 16 + x), F);
  }
  __syncthreads();

  // conv1 + gelu -> sm: thread = (pixel p, oc-group og of 32)
  {
    int p = tid & 255, og = tid >> 8;
    int ii = p >> 4, jj = p & 15;
    float pin[27];
    #pragma unroll
    for (int c = 0; c < 3; c++)
      #pragma unroll
      for (int dy = 0; dy < 3; dy++)
        #pragma unroll
        for (int dx = 0; dx < 3; dx++){
          int y = ii + dy - 1, x = jj + dx - 1;
          bool ok = (y >= 0 && y < 16 && x >= 0 && x < 16);
          pin[c * 9 + dy * 3 + dx] = ok ? timg[c * 256 + y * 16 + x] : 0.f;
        }
    for (int o = 0; o < 32; o++){
      int oc = og * 32 + o;
      float a = B1[oc];
      #pragma unroll
      for (int t = 0; t < 27; t++) a += W1[oc * 27 + t] * pin[t];
      sm[oc * 256 + p] = gelu_f(a);
    }
  }
  __syncthreads();

  // conv2: wave w (0..7) x half h (0..1) -> 8 oc; lane = 4 consecutive px in a row
  int wv = tid >> 6, ln = tid & 63;
  int row = ln >> 2, cg = ln & 3;
  int c0 = cg * 4;   // first pixel col of this lane's group

  for (int h = 0; h < 2; h++){
    int oc0 = h * 64 + wv * 8;
    float acc[4][8];
    #pragma unroll
    for (int o = 0; o < 8; o++){
      float bz = B2[oc0 + o];
      #pragma unroll
      for (int j = 0; j < 4; j++) acc[j][o] = bz;
    }
    const float* wg = W2 + ((size_t)(h * 8 + wv)) * 4608;   // [ic][ocl][9]
    for (int ic = 0; ic < 64; ic++){
      float win[3][6];
      #pragma unroll
      for (int r = 0; r < 3; r++){
        int y = row - 1 + r;
        bool yok = (y >= 0 && y < 16);
        #pragma unroll
        for (int cc = 0; cc < 6; cc++){
          int x = c0 - 1 + cc;
          win[r][cc] = (yok && x >= 0 && x < 16) ? sm[ic * 256 + y * 16 + x] : 0.f;
        }
      }
      const float* wp = wg + (size_t)ic * 72;   // 72 contiguous wave-uniform floats
      #pragma unroll
      for (int o = 0; o < 8; o++){
        #pragma unroll
        for (int t9 = 0; t9 < 9; t9++){
          int dy = t9 / 3, dx = t9 - dy * 3;
          float wvv = wp[o * 9 + t9];
          #pragma unroll
          for (int j = 0; j < 4; j++)
            acc[j][o] += wvv * win[dy][j + dx];
        }
      }
    }
    // gelu + pool: lane sums its 4 px, wave-reduce over 64 lanes (256 px total)
    #pragma unroll
    for (int o = 0; o < 8; o++){
      float g = gelu_f(acc[0][o]) + gelu_f(acc[1][o]) + gelu_f(acc[2][o]) + gelu_f(acc[3][o]);
      g += __shfl_xor(g, 1);  g += __shfl_xor(g, 2);  g += __shfl_xor(g, 4);
      g += __shfl_xor(g, 8);  g += __shfl_xor(g, 16); g += __shfl_xor(g, 32);
      if (ln == 0) pool[oc0 + o] = g;   // waves own disjoint oc, no merge needed
    }
  }
  __syncthreads();
  if (tid < 128) pm[tid] = pool[tid] * (1.f / 256.f);
  __syncthreads();

  // fc 128 -> 256 (threads 0..255)
  if (tid < 256){
    int df = tid;
    float s = FCB[df];
    const float* wrow = FCW + (size_t)df * 128;
    #pragma unroll
    for (int k = 0; k < 128; k += 4)
      s += wrow[k] * pm[k] + wrow[k + 1] * pm[k + 1]
         + wrow[k + 2] * pm[k + 2] + wrow[k + 3] * pm[k + 3];
    feats[((size_t)(b * 1024 + pidx)) * 256 + df] = s;
  }
}

// ---------------- K2: g_proj / g_prime, wave-per-row coalesced ----------------------
__global__ __launch_bounds__(256) void k_gmm(const void* __restrict__ lang,
                                             const void* __restrict__ wgate,
                                             const void* __restrict__ wgp,
                                             float* __restrict__ ws)
{
  const int F = ((const int*)(ws + O_FLAG))[0];
  int row = blockIdx.x * 4 + (threadIdx.x >> 6);
  int lane = threadIdx.x & 63;
  int mat = row >> 9;
  int b   = (row >> 8) & 1;
  int df  = row & 255;
  const void* W = mat ? wgp : wgate;
  float s = 0.f;
  for (int k = lane; k < 896; k += 64)
    s += ldin(lang, (size_t)b * 896 + k, F) * ldin(W, (size_t)df * 896 + k, F);
  s += __shfl_xor(s, 1);  s += __shfl_xor(s, 2);  s += __shfl_xor(s, 4);
  s += __shfl_xor(s, 8);  s += __shfl_xor(s, 16); s += __shfl_xor(s, 32);
  if (lane == 0) ws[(mat ? O_GPRIM : O_GPROJ) + b * 256 + df] = s;
}

// ---------------- K3: structure (rsem fused + Boruvka MST + adjacency + level BFS) ---
__device__ __forceinline__ void edge_uv(int e, int& u, int& v){
  if (e < 1953){
    int i = e / 63; int k = e - i * 63;
    if (k < 62){ int j = k >> 1; u = i * 32 + j; v = (k & 1) ? u + 32 : u + 1; }
    else { u = i * 32 + 31; v = u + 32; }
  } else { u = 31 * 32 + (e - 1953); v = u + 1; }
}

__global__ __launch_bounds__(1024) void k_struct(float* __restrict__ ws)
{
  __shared__ float s_ninv[1024];
  __shared__ float s_w[NEDGE];
  __shared__ float s_r[1024];
  __shared__ int   s_comp[1024];
  __shared__ int   s_link[1024];
  __shared__ int   s_link2[1024];
  __shared__ unsigned long long s_best[1024];
  __shared__ unsigned char  s_mst[NEDGE];
  __shared__ unsigned short s_adj[1024 * 4];
  __shared__ unsigned char  s_deg[1024];
  __shared__ unsigned short s_bfs[1024];
  __shared__ short          s_parof[1024];
  __shared__ unsigned short s_o2b[1024];
  __shared__ unsigned short s_cur[1024];
  __shared__ unsigned short s_nxt[1024];
  __shared__ unsigned short s_off[1025];
  __shared__ unsigned long long s_rootkey;
  __shared__ int s_ncomp, s_cursz, s_bfscnt, s_nextsz;

  int b = blockIdx.x; int tid = threadIdx.x;
  const float* feats = ws + O_FEATS + (size_t)b * NP * DFEAT;

  // norms + fused r_sem (one pass over the thread's feats row) + defensive init
  {
    const float4* f4 = (const float4*)(feats + (size_t)tid * 256);
    const float4* g4 = (const float4*)(ws + O_GPROJ + b * 256);
    float d = 0.f, gdot = 0.f;
    for (int k = 0; k < 64; k++){
      float4 q = f4[k]; float4 g = g4[k];
      d += q.x*q.x + q.y*q.y + q.z*q.z + q.w*q.w;
      gdot += q.x*g.x + q.y*g.y + q.z*g.z + q.w*g.w;
    }
    s_ninv[tid] = 1.f / fmaxf(sqrtf(d), 1e-12f);
    float r = 1.f / (1.f + expf(-gdot * (1.f / 16.f)));
    s_r[tid] = r;
    ws[O_RSEM + b * NP + tid] = r;      // k_xdelta consumes this
    s_comp[tid] = tid;
    s_deg[tid] = 0;
    s_bfs[tid] = (unsigned short)tid;
    s_o2b[tid] = (unsigned short)tid;
    s_parof[tid] = -1;
  }
  for (int e = tid; e < NEDGE; e += 1024) s_mst[e] = 0;
  __syncthreads();

  // edge weights
  for (int e = tid; e < NEDGE; e += 1024){
    int u, v; edge_uv(e, u, v);
    const float4* fu = (const float4*)(feats + (size_t)u * 256);
    const float4* fv = (const float4*)(feats + (size_t)v * 256);
    float d = 0.f;
    for (int k = 0; k < 64; k++){ float4 a = fu[k], c = fv[k]; d += a.x*c.x + a.y*c.y + a.z*c.z + a.w*c.w; }
    float cosv = d * s_ninv[u] * s_ninv[v];
    s_w[e] = (1.f - s_r[u]) * (1.f - s_r[v]) * (-cosv) + 1e-6f;
  }
  __syncthreads();

  // Boruvka rounds
  for (int round = 0; round < 12; round++){
    s_best[tid] = ~0ull;
    __syncthreads();
    for (int e = tid; e < NEDGE; e += 1024){
      int u, v; edge_uv(e, u, v);
      int cu = s_comp[u], cv = s_comp[v];
      if (cu != cv){
        unsigned long long key = (((unsigned long long)f2sort(s_w[e])) << 32) | (unsigned int)e;
        atomicMin(&s_best[cu], key);
        atomicMin(&s_best[cv], key);
      }
    }
    __syncthreads();
    int l = tid;
    if (s_comp[tid] == tid && s_best[tid] != ~0ull){
      int e = (int)(s_best[tid] & 0xffffffffu);
      int u, v; edge_uv(e, u, v);
      s_mst[e] = 1;
      int cu = s_comp[u], cv = s_comp[v];
      l = (cu == tid) ? cv : cu;
    }
    s_link[tid] = l;
    __syncthreads();
    if (l != tid && s_link[l] == tid && tid < l) s_link[tid] = tid; // break 2-cycles
    __syncthreads();
    for (int it = 0; it < 10; it++){      // pointer jumping (double-buffered)
      int x = s_link[tid]; s_link2[tid] = s_link[x];
      __syncthreads();
      s_link[tid] = s_link2[tid];
      __syncthreads();
    }
    s_comp[tid] = s_link[s_comp[tid]];
    if (tid == 0) s_ncomp = 0;
    __syncthreads();
    if (s_comp[tid] == tid) atomicAdd(&s_ncomp, 1);
    __syncthreads();
    if (s_ncomp == 1) break;
    __syncthreads();
  }
  __syncthreads();

  // weight-ordered adjacency (== Kruskal insertion order for unique MST)
  {
    int v = tid; int i = v >> 5, j = v & 31;
    float wloc[4]; int nloc[4]; int d = 0;
    if (j > 0){ int e = (i < 31) ? (i * 63 + 2 * (j - 1)) : (1953 + (j - 1));
      if (s_mst[e]){ wloc[d] = s_w[e]; nloc[d] = v - 1; d++; } }
    if (j < 31){ int e = (i < 31) ? (i * 63 + 2 * j) : (1953 + j);
      if (s_mst[e]){ wloc[d] = s_w[e]; nloc[d] = v + 1; d++; } }
    if (i > 0){ int e = (i - 1) * 63 + ((j < 31) ? (2 * j + 1) : 62);
      if (s_mst[e]){ wloc[d] = s_w[e]; nloc[d] = v - 32; d++; } }
    if (i < 31){ int e = i * 63 + ((j < 31) ? (2 * j + 1) : 62);
      if (s_mst[e]){ wloc[d] = s_w[e]; nloc[d] = v + 32; d++; } }
    for (int a = 1; a < d; a++){
      float wv = wloc[a]; int nv = nloc[a]; int c = a - 1;
      while (c >= 0 && wloc[c] > wv){ wloc[c+1] = wloc[c]; nloc[c+1] = nloc[c]; c--; }
      wloc[c+1] = wv; nloc[c+1] = nv;
    }
    s_deg[v] = (unsigned char)d;
    for (int a = 0; a < d; a++) s_adj[v * 4 + a] = (unsigned short)nloc[a];
  }
  // root = argmax r (first index on ties)
  if (tid == 0) s_rootkey = 0ull;
  __syncthreads();
  {
    unsigned long long key = (((unsigned long long)f2sort(s_r[tid])) << 32) | (unsigned int)(1023 - tid);
    atomicMax(&s_rootkey, key);
  }
  __syncthreads();
  int root = 1023 - (int)(s_rootkey & 0xffffffffu);

  // level-parallel tree BFS
  if (tid == 0){
    s_bfs[0] = (unsigned short)root; s_o2b[root] = 0; s_parof[root] = -1;
    s_cur[0] = (unsigned short)root; s_cursz = 1; s_bfscnt = 1;
  }
  __syncthreads();
  for (int lev = 0; lev < 1024; lev++){
    int csz = s_cursz;
    if (csz <= 0) break;
    // wave-parallel exclusive scan of child counts
    if (tid < 64){
      int runbase = 0;
      for (int t0 = 0; t0 < csz; t0 += 64){
        int t = t0 + tid;
        int cnt = 0;
        if (t < csz){
          int n = s_cur[t];
          cnt = (int)s_deg[n] - (s_parof[n] >= 0 ? 1 : 0);
        }
        int v = cnt;
        #pragma unroll
        for (int off = 1; off < 64; off <<= 1){
          int u2 = __shfl_up(v, off);
          if (tid >= off) v += u2;
        }
        if (t < csz) s_off[t] = (unsigned short)(runbase + v - cnt);
        runbase += __shfl(v, 63);
      }
      if (tid == 0) s_nextsz = runbase;
    }
    __syncthreads();
    if (tid < csz){
      int n = s_cur[tid]; int base = s_off[tid]; int k = 0;
      int pn = s_parof[n]; int dg = s_deg[n];
      for (int a = 0; a < dg; a++){
        int c = s_adj[n * 4 + a];
        if (c == pn) continue;
        s_parof[c] = (short)n;
        if (base + k < 1024) s_nxt[base + k] = (unsigned short)c;
        int pos = s_bfscnt + base + k;
        if (pos < 1024){
          s_bfs[pos] = (unsigned short)c;
          s_o2b[c] = (unsigned short)pos;
        }
        k++;
      }
    }
    __syncthreads();
    if (tid == 0){ s_bfscnt += s_nextsz; s_cursz = (s_nextsz > 1024) ? 1024 : s_nextsz; }
    __syncthreads();
    if (tid < s_cursz) s_cur[tid] = s_nxt[tid];
    __syncthreads();
  }
  __syncthreads();

  int* BFSo = (int*)(ws + O_BFS);
  int* PARo = (int*)(ws + O_PAR);
  {
    int node = s_bfs[tid] & 1023;
    BFSo[b * 1024 + tid] = node;
    int p = s_parof[node];
    PARo[b * 1024 + tid] = (p < 0) ? -1 : (int)(s_o2b[p] & 1023);
  }
}

// ---------------- K4: X, delta, Bp, Cp (k-major coalesced weight reads, R13) ---------
__global__ __launch_bounds__(256) void k_xdelta(float* __restrict__ ws)
{
  __shared__ float xs[256];
  int blk = blockIdx.x; int b = blk >> 10, i = blk & 1023; int df = threadIdx.x;
  const int* BFSo = (const int*)(ws + O_BFS);
  int node = BFSo[b * 1024 + i] & 1023;
  float rs = ws[O_RSEM + b * 1024 + node];
  float xv = ws[O_FEATS + ((size_t)(b * 1024 + node)) * 256 + df] + rs * ws[O_GPRIM + b * 256 + df];
  xs[df] = xv;
  ws[O_X + ((size_t)(b * 1024 + i)) * 256 + df] = xv;
  __syncthreads();
  {
    // z = WDB[df] + sum_k WDW_T[k][df]*xs[k]: coalesced load + LDS broadcast per k
    const float* WT = ws + O_WDW;
    float z = ws[O_WDB + df];
    #pragma unroll 8
    for (int k = 0; k < 256; k++)
      z += WT[(size_t)k * 256 + df] * xs[k];
    float sp = fmaxf(z, 0.f) + log1pf(expf(-fabsf(z)));
    ws[O_DELTA + ((size_t)(b * 1024 + i)) * 256 + df] = sp * (1.f + 2.f * rs);
  }
  if (df < 32){
    int s = df & 15;
    const float* WT = ws + ((df < 16) ? O_BWO : O_CWO);   // [k][s]
    float a = ws[((df < 16) ? O_BBO : O_CBO) + s];
    #pragma unroll 8
    for (int k = 0; k < 256; k++) a += WT[k * 16 + s] * xs[k];
    ws[((df < 16) ? O_BP : O_CP) + (size_t)(b * 1024 + i) * 16 + s] = a;
  }
}

// ---------------- K5: tree scan, LDS history; 4-deep B/C prefetch --------------------
__global__ __launch_bounds__(64) void k_scan(float* __restrict__ ws)
{
  __shared__ float h[NP * DSTATE];   // 64 KB: h[pos][s]
  __shared__ float xs[NP];
  __shared__ float ds[NP];
  __shared__ int   par_s[NP];
  __shared__ int   bfs_s[NP];
  int blk = blockIdx.x; int b = blk >> 8, f = blk & 255;
  int lane = threadIdx.x;
  const int* PARo = (const int*)(ws + O_PAR);
  const int* BFSo = (const int*)(ws + O_BFS);
  for (int i = lane; i < NP; i += 64){
    xs[i] = ws[O_X     + ((size_t)(b * NP + i)) * DFEAT + f];
    ds[i] = ws[O_DELTA + ((size_t)(b * NP + i)) * DFEAT + f];
    par_s[i] = PARo[b * NP + i];
    bfs_s[i] = BFSo[b * NP + i] & 1023;
  }
  __syncthreads();
  if (lane < 16){
    int s = lane;
    float Aln = ws[O_AF + f * 16 + s];
    float Dv  = ws[O_DD + f];
    const float* Bp = ws + O_BP + (size_t)b * NP * DSTATE;
    const float* Cp = ws + O_CP + (size_t)b * NP * DSTATE;
    float* Yr = ws + O_YR + (size_t)b * NP * DFEAT;
    float bvr[4], cvr[4];
    #pragma unroll
    for (int k = 0; k < 4; k++){ bvr[k] = Bp[k * 16 + s]; cvr[k] = Cp[k * 16 + s]; }
    #pragma unroll 4
    for (int i = 0; i < NP; i++){
      float bv = bvr[i & 3], cv = cvr[i & 3];
      int ip = i + 4;
      if (ip < NP){ bvr[i & 3] = Bp[ip * 16 + s]; cvr[i & 3] = Cp[ip * 16 + s]; }
      int p = par_s[i];
      float d = ds[i], x = xs[i];
      float hp = (p >= 0) ? h[p * 16 + s] : 0.f;
      float hn = expf(d * Aln) * hp + d * bv * x;
      h[i * 16 + s] = hn;
      float t = hn * cv;
      t += __shfl_xor(t, 1); t += __shfl_xor(t, 2);
      t += __shfl_xor(t, 4); t += __shfl_xor(t, 8);
      if (s == 0) Yr[(size_t)bfs_s[i] * DFEAT + f] = t + Dv * x;
    }
  }
}

// ---------------- K6: out GEMM (k-major coalesced) + LayerNorm -> out dtype ----------
__global__ __launch_bounds__(256) void k_outln(const float* __restrict__ ws,
                                               void* __restrict__ out)
{
  __shared__ float yl[256];
  __shared__ float red[8];
  const int F = ((const int*)(ws + O_FLAG))[0];
  int blk = blockIdx.x; int b = blk >> 10, p = blk & 1023; int df = threadIdx.x;
  yl[df] = ws[O_YR + ((size_t)(b * 1024 + p)) * 256 + df];
  __syncthreads();
  const float* OT = ws + O_OW;   // [k][df]
  float a = ws[O_OB + df];
  #pragma unroll 8
  for (int k = 0; k < 256; k++)
    a += OT[(size_t)k * 256 + df] * yl[k];
  int lane = df & 63, wid = df >> 6;
  float t = a;
  t += __shfl_xor(t, 1); t += __shfl_xor(t, 2);  t += __shfl_xor(t, 4);
  t += __shfl_xor(t, 8); t += __shfl_xor(t, 16); t += __shfl_xor(t, 32);
  if (lane == 0) red[wid] = t;
  __syncthreads();
  float mu = (red[0] + red[1] + red[2] + red[3]) * (1.f / 256.f);
  float dv = a - mu;
  float t2 = dv * dv;
  t2 += __shfl_xor(t2, 1); t2 += __shfl_xor(t2, 2);  t2 += __shfl_xor(t2, 4);
  t2 += __shfl_xor(t2, 8); t2 += __shfl_xor(t2, 16); t2 += __shfl_xor(t2, 32);
  if (lane == 0) red[4 + wid] = t2;
  __syncthreads();
  float var = (red[4] + red[5] + red[6] + red[7]) * (1.f / 256.f);
  float o = ws[O_LNG + df] * dv / sqrtf(var + 1e-5f) + ws[O_LNB + df];
  size_t idx = ((size_t)(b * 1024 + p)) * 256 + df;
  if (F) ((ushortb*)out)[idx] = f2bf(o);
  else   ((float*)out)[idx]   = o;
}

// ---------------- launch ----------------
extern "C" void kernel_launch(void* const* d_in, const int* in_sizes, int n_in,
                              void* d_out, int out_size, void* d_ws, size_t ws_size,
                              hipStream_t stream)
{
  (void)in_sizes; (void)n_in; (void)out_size; (void)ws_size;
  const void* img   = d_in[0];
  const void* lang  = d_in[1];
  const void* c1w   = d_in[2];
  const void* c1b   = d_in[3];
  const void* c2w   = d_in[4];
  const void* c2b   = d_in[5];
  const void* fcw   = d_in[6];
  const void* fcb   = d_in[7];
  const void* wgate = d_in[8];
  const void* wgp   = d_in[9];
  const void* alog  = d_in[10];
  const void* dvec  = d_in[11];
  const void* bw    = d_in[12];
  const void* bb    = d_in[13];
  const void* cw    = d_in[14];
  const void* cb    = d_in[15];
  const void* wdw   = d_in[16];
  const void* wdb   = d_in[17];
  const void* ow    = d_in[18];
  const void* ob    = d_in[19];
  const void* lng   = d_in[20];
  const void* lnb   = d_in[21];
  float* ws = (float*)d_ws;

  k_sniff<<<1, 256, 0, stream>>>(img, ws);
  k_convert<<<990 + 2048, 256, 0, stream>>>(c1w, c1b, c2w, c2b, fcw, fcb, alog, dvec,
                                            bw, bb, cw, cb, wdw, wdb, ow, ob, lng, lnb, ws);
  k_patch<<<2048, 512, 0, stream>>>(img, ws, ws + O_FEATS);
  k_gmm<<<256, 256, 0, stream>>>(lang, wgate, wgp, ws);
  k_struct<<<2, 1024, 0, stream>>>(ws);
  k_xdelta<<<2048, 256, 0, stream>>>(ws);
  k_scan<<<NB * DFEAT, 64, 0, stream>>>(ws);
  k_outln<<<2048, 256, 0, stream>>>(ws, d_out);
}

// Round 14
// 1993.674 us; speedup vs baseline: 1.6129x; 1.1434x over previous
//
#include <hip/hip_runtime.h>
#include <cstddef>
#include <cstdint>

// ---------------- constants ----------------
#define NB    2
#define NP    1024    // patches per image
#define DFEAT 256
#define DSTATE 16
#define NEDGE 1984    // grid edges: 31*63 + 31

typedef unsigned short ushortb;

// ---------------- helpers ----------------
__device__ __forceinline__ float bf2f(unsigned short u){
  union { unsigned int i; float f; } c; c.i = ((unsigned int)u) << 16; return c.f;
}
__device__ __forceinline__ unsigned short f2bf(float f){
  union { float f; unsigned int i; } c; c.f = f;
  unsigned int u = c.i;
  unsigned int r = (u + 0x7fffu + ((u >> 16) & 1u)) >> 16;
  return (unsigned short)r;
}
// dtype-generic input load: isbf ? bf16[i] : fp32[i]
__device__ __forceinline__ float ldin(const void* p, size_t i, int isbf){
  return isbf ? bf2f(((const ushortb*)p)[i]) : ((const float*)p)[i];
}
__device__ __forceinline__ float gelu_f(float x){
  return 0.5f * x * (1.0f + erff(x * 0.70710678118654752f));
}
__device__ __forceinline__ unsigned int f2sort(float f){
  union { float f; unsigned int i; } c; c.f = f;
  return (c.i & 0x80000000u) ? ~c.i : (c.i | 0x80000000u);
}

// ---------------- ws layout (float element offsets) ----------------
constexpr size_t AL(size_t x){ return (x + 63) & ~(size_t)63; }
constexpr size_t O_W1    = 0;                       // 1728  conv1 w fp32
constexpr size_t O_B1    = AL(O_W1 + 1728);         // 64
constexpr size_t O_W2    = AL(O_B1 + 64);           // 73728 conv2 w fp32, layout [g][ic][ocl][9]
constexpr size_t O_B2    = AL(O_W2 + 73728);        // 128
constexpr size_t O_FCW   = AL(O_B2 + 128);          // 32768 [df][128]
constexpr size_t O_FCB   = AL(O_FCW + 32768);       // 256
constexpr size_t O_WDW   = AL(O_FCB + 256);         // 65536 TRANSPOSED [k][df]
constexpr size_t O_WDB   = AL(O_WDW + 65536);       // 256
constexpr size_t O_BWO   = AL(O_WDB + 256);         // 4096 TRANSPOSED [k][s]
constexpr size_t O_BBO   = AL(O_BWO + 4096);        // 16
constexpr size_t O_CWO   = AL(O_BBO + 16);          // 4096 TRANSPOSED [k][s]
constexpr size_t O_CBO   = AL(O_CWO + 4096);        // 16
constexpr size_t O_OW    = AL(O_CBO + 16);          // 65536 TRANSPOSED [k][df]
constexpr size_t O_OB    = AL(O_OW + 65536);        // 256
constexpr size_t O_AF    = AL(O_OB + 256);          // 4096  A = -exp(A_log), [f][s]
constexpr size_t O_DD    = AL(O_AF + 4096);         // 256
constexpr size_t O_LNG   = AL(O_DD + 256);          // 256
constexpr size_t O_LNB   = AL(O_LNG + 256);         // 256
constexpr size_t O_FEATS = AL(O_LNB + 256);         // 2*1024*256
constexpr size_t O_GPROJ = AL(O_FEATS + (size_t)NB*NP*DFEAT); // 512
constexpr size_t O_GPRIM = AL(O_GPROJ + NB*DFEAT);  // 512
constexpr size_t O_RSEM  = AL(O_GPRIM + NB*DFEAT);  // 2048
constexpr size_t O_BFS   = AL(O_RSEM + NB*NP);      // 2048 (int)
constexpr size_t O_PAR   = AL(O_BFS + NB*NP);       // 2048 (int)
constexpr size_t O_X     = AL(O_PAR + NB*NP);       // 2*1024*256
constexpr size_t O_DELTA = AL(O_X + (size_t)NB*NP*DFEAT);
constexpr size_t O_BP    = AL(O_DELTA + (size_t)NB*NP*DFEAT); // 2*1024*16
constexpr size_t O_CP    = AL(O_BP + NB*NP*DSTATE);
constexpr size_t O_YR    = AL(O_CP + NB*NP*DSTATE); // 2*1024*256
constexpr size_t O_FLAG  = AL(O_YR + (size_t)NB*NP*DFEAT);    // 1 int: is-bf16 flag
constexpr size_t O_LVL   = AL(O_FLAG + 64);         // NB*1040 ints: [nlvl, loff[0..nlvl]]

// ---------------- K-1: sniff input dtype (bf16 vs fp32) from images buffer -----------
__global__ __launch_bounds__(256) void k_sniff(const void* img, float* ws)
{
  __shared__ int cnt;
  int tid = threadIdx.x;
  if (tid == 0) cnt = 0;
  __syncthreads();
  const ushortb* u = (const ushortb*)img;
  int local = 0;
  for (int k = 0; k < 16; k++){
    unsigned short v = u[tid * 16 + k];
    if (v == 0 || v == 0x8000u){ local++; continue; }
    float f = fabsf(bf2f(v));
    if (f >= 1e-8f && f <= 64.f) local++;    // plausible N(0,1) bf16
  }
  atomicAdd(&cnt, local);
  __syncthreads();
  if (tid == 0) ((int*)(ws + O_FLAG))[0] = (cnt >= 3900) ? 1 : 0;  // >=95% plausible
}

// ---------------- K0: convert weights -> fp32 + zero-init YR (fused) ------------
__global__ void k_convert(const void* c1w, const void* c1b, const void* c2w,
                          const void* c2b, const void* fcw, const void* fcb,
                          const void* alog, const void* dvec,
                          const void* bw, const void* bb, const void* cw, const void* cb,
                          const void* wdw, const void* wdb,
                          const void* ow, const void* ob,
                          const void* lng, const void* lnb, float* ws)
{
  const int F = ((const int*)(ws + O_FLAG))[0];
  if (blockIdx.x >= 990){   // init branch: zero YR
    size_t i2 = (size_t)(blockIdx.x - 990) * 256 + threadIdx.x;
    if (i2 < (size_t)NB * NP * DFEAT) ws[O_YR + i2] = 0.f;
    return;
  }
  int i = blockIdx.x * 256 + threadIdx.x;
  if (i < 1728){ ws[O_W1 + i] = ldin(c1w, i, F); return; } i -= 1728;
  if (i < 64){ ws[O_B1 + i] = ldin(c1b, i, F); return; } i -= 64;
  if (i < 73728){
    // dst layout [g=0..15][ic=0..63][ocl=0..7][9]: i = ((g*64+ic)*8+ocl)*9 + t
    int g = i / 4608; int r = i - g * 4608;
    int ic = r / 72;  int r2 = r - ic * 72;
    int ocl = r2 / 9; int t = r2 - ocl * 9;
    int oc = (g >> 3) * 64 + (g & 7) * 8 + ocl;
    ws[O_W2 + i] = ldin(c2w, (size_t)(oc * 64 + ic) * 9 + t, F); return;
  } i -= 73728;
  if (i < 128){ ws[O_B2 + i] = ldin(c2b, i, F); return; } i -= 128;
  if (i < 32768){ ws[O_FCW + i] = ldin(fcw, i, F); return; } i -= 32768;
  if (i < 256){ ws[O_FCB + i] = ldin(fcb, i, F); return; } i -= 256;
  if (i < 65536){  // WDW transposed: dst[k*256+df] = src[df*256+k]
    int k = i >> 8, df = i & 255;
    ws[O_WDW + i] = ldin(wdw, (size_t)df * 256 + k, F); return;
  } i -= 65536;
  if (i < 256){ ws[O_WDB + i] = ldin(wdb, i, F); return; } i -= 256;
  if (i < 4096){   // B_w transposed: dst[k*16+s] = src[s*256+k]
    int k = i >> 4, s = i & 15;
    ws[O_BWO + i] = ldin(bw, (size_t)s * 256 + k, F); return;
  } i -= 4096;
  if (i < 16){ ws[O_BBO + i] = ldin(bb, i, F); return; } i -= 16;
  if (i < 4096){   // C_w transposed
    int k = i >> 4, s = i & 15;
    ws[O_CWO + i] = ldin(cw, (size_t)s * 256 + k, F); return;
  } i -= 4096;
  if (i < 16){ ws[O_CBO + i] = ldin(cb, i, F); return; } i -= 16;
  if (i < 65536){  // out_w transposed: dst[k*256+df] = src[df*256+k]
    int k = i >> 8, df = i & 255;
    ws[O_OW + i] = ldin(ow, (size_t)df * 256 + k, F); return;
  } i -= 65536;
  if (i < 256){ ws[O_OB + i] = ldin(ob, i, F); return; } i -= 256;
  if (i < 4096){ ws[O_AF + i] = -expf(ldin(alog, i, F)); return; } i -= 4096;
  if (i < 256){ ws[O_DD + i] = ldin(dvec, i, F); return; } i -= 256;
  if (i < 256){ ws[O_LNG + i] = ldin(lng, i, F); return; } i -= 256;
  if (i < 256){ ws[O_LNB + i] = ldin(lnb, i, F); return; }
}

// ---------------- K1: per-patch conv1+gelu+conv2+gelu+pool+fc (R8 verbatim) ----------
__global__ __launch_bounds__(512, 4) void k_patch(const void* __restrict__ img,
                                                  const float* __restrict__ ws,
                                                  float* __restrict__ feats)
{
  __shared__ float sm[64 * 256];  // 64KB: h1 [64 ic][256 px]
  __shared__ float timg[768];     // 3KB input tile [3 c][256 px]
  __shared__ float pool[128];     // pooled sums per oc
  __shared__ float pm[128];       // pooled mean
  const int F = ((const int*)(ws + O_FLAG))[0];
  const float* W1 = ws + O_W1;  const float* B1 = ws + O_B1;
  const float* W2 = ws + O_W2;  const float* B2 = ws + O_B2;
  const float* FCW = ws + O_FCW; const float* FCB = ws + O_FCB;

  int blk = blockIdx.x; int b = blk >> 10; int pidx = blk & 1023;
  int ph = pidx >> 5, pw = pidx & 31;
  int tid = threadIdx.x;

  // stage input tile (16x16x3) into LDS
  if (tid < 256){
    int y = tid >> 4, x = tid & 15;
    #pragma unroll
    for (int c = 0; c < 3; c++)
      timg[c * 256 + tid] =
        ldin(img, (((size_t)b * 3 + c) * 512 + (ph * 16 + y)) * 512 + (pw * 16 + x), F);
  }
  __syncthreads();

  // conv1 + gelu -> sm: thread = (pixel p, oc-group og of 32)
  {
    int p = tid & 255, og = tid >> 8;
    int ii = p >> 4, jj = p & 15;
    float pin[27];
    #pragma unroll
    for (int c = 0; c < 3; c++)
      #pragma unroll
      for (int dy = 0; dy < 3; dy++)
        #pragma unroll
        for (int dx = 0; dx < 3; dx++){
          int y = ii + dy - 1, x = jj + dx - 1;
          bool ok = (y >= 0 && y < 16 && x >= 0 && x < 16);
          pin[c * 9 + dy * 3 + dx] = ok ? timg[c * 256 + y * 16 + x] : 0.f;
        }
    for (int o = 0; o < 32; o++){
      int oc = og * 32 + o;
      float a = B1[oc];
      #pragma unroll
      for (int t = 0; t < 27; t++) a += W1[oc * 27 + t] * pin[t];
      sm[oc * 256 + p] = gelu_f(a);
    }
  }
  __syncthreads();

  // conv2: wave w (0..7) x half h (0..1) -> 8 oc; lane = 4 consecutive px in a row
  int wv = tid >> 6, ln = tid & 63;
  int row = ln >> 2, cg = ln & 3;
  int c0 = cg * 4;   // first pixel col of this lane's group

  for (int h = 0; h < 2; h++){
    int oc0 = h * 64 + wv * 8;
    float acc[4][8];
    #pragma unroll
    for (int o = 0; o < 8; o++){
      float bz = B2[oc0 + o];
      #pragma unroll
      for (int j = 0; j < 4; j++) acc[j][o] = bz;
    }
    const float* wg = W2 + ((size_t)(h * 8 + wv)) * 4608;   // [ic][ocl][9]
    for (int ic = 0; ic < 64; ic++){
      float win[3][6];
      #pragma unroll
      for (int r = 0; r < 3; r++){
        int y = row - 1 + r;
        bool yok = (y >= 0 && y < 16);
        #pragma unroll
        for (int cc = 0; cc < 6; cc++){
          int x = c0 - 1 + cc;
          win[r][cc] = (yok && x >= 0 && x < 16) ? sm[ic * 256 + y * 16 + x] : 0.f;
        }
      }
      const float* wp = wg + (size_t)ic * 72;   // 72 contiguous wave-uniform floats
      #pragma unroll
      for (int o = 0; o < 8; o++){
        #pragma unroll
        for (int t9 = 0; t9 < 9; t9++){
          int dy = t9 / 3, dx = t9 - dy * 3;
          float wvv = wp[o * 9 + t9];
          #pragma unroll
          for (int j = 0; j < 4; j++)
            acc[j][o] += wvv * win[dy][j + dx];
        }
      }
    }
    // gelu + pool: lane sums its 4 px, wave-reduce over 64 lanes (256 px total)
    #pragma unroll
    for (int o = 0; o < 8; o++){
      float g = gelu_f(acc[0][o]) + gelu_f(acc[1][o]) + gelu_f(acc[2][o]) + gelu_f(acc[3][o]);
      g += __shfl_xor(g, 1);  g += __shfl_xor(g, 2);  g += __shfl_xor(g, 4);
      g += __shfl_xor(g, 8);  g += __shfl_xor(g, 16); g += __shfl_xor(g, 32);
      if (ln == 0) pool[oc0 + o] = g;   // waves own disjoint oc, no merge needed
    }
  }
  __syncthreads();
  if (tid < 128) pm[tid] = pool[tid] * (1.f / 256.f);
  __syncthreads();

  // fc 128 -> 256 (threads 0..255)
  if (tid < 256){
    int df = tid;
    float s = FCB[df];
    const float* wrow = FCW + (size_t)df * 128;
    #pragma unroll
    for (int k = 0; k < 128; k += 4)
      s += wrow[k] * pm[k] + wrow[k + 1] * pm[k + 1]
         + wrow[k + 2] * pm[k + 2] + wrow[k + 3] * pm[k + 3];
    feats[((size_t)(b * 1024 + pidx)) * 256 + df] = s;
  }
}

// ---------------- K2: g_proj / g_prime, wave-per-row coalesced ----------------------
__global__ __launch_bounds__(256) void k_gmm(const void* __restrict__ lang,
                                             const void* __restrict__ wgate,
                                             const void* __restrict__ wgp,
                                             float* __restrict__ ws)
{
  const int F = ((const int*)(ws + O_FLAG))[0];
  int row = blockIdx.x * 4 + (threadIdx.x >> 6);
  int lane = threadIdx.x & 63;
  int mat = row >> 9;
  int b   = (row >> 8) & 1;
  int df  = row & 255;
  const void* W = mat ? wgp : wgate;
  float s = 0.f;
  for (int k = lane; k < 896; k += 64)
    s += ldin(lang, (size_t)b * 896 + k, F) * ldin(W, (size_t)df * 896 + k, F);
  s += __shfl_xor(s, 1);  s += __shfl_xor(s, 2);  s += __shfl_xor(s, 4);
  s += __shfl_xor(s, 8);  s += __shfl_xor(s, 16); s += __shfl_xor(s, 32);
  if (lane == 0) ws[(mat ? O_GPRIM : O_GPROJ) + b * 256 + df] = s;
}

// ---------------- K3: structure (rsem fused + Boruvka MST + adjacency + level BFS) ---
// R14: exports BFS level offsets (free: s_bfscnt per level) for level-parallel k_scan.
__device__ __forceinline__ void edge_uv(int e, int& u, int& v){
  if (e < 1953){
    int i = e / 63; int k = e - i * 63;
    if (k < 62){ int j = k >> 1; u = i * 32 + j; v = (k & 1) ? u + 32 : u + 1; }
    else { u = i * 32 + 31; v = u + 32; }
  } else { u = 31 * 32 + (e - 1953); v = u + 1; }
}

__global__ __launch_bounds__(1024) void k_struct(float* __restrict__ ws)
{
  __shared__ float s_ninv[1024];
  __shared__ float s_w[NEDGE];
  __shared__ float s_r[1024];
  __shared__ int   s_comp[1024];
  __shared__ int   s_link[1024];
  __shared__ int   s_link2[1024];
  __shared__ unsigned long long s_best[1024];
  __shared__ unsigned char  s_mst[NEDGE];
  __shared__ unsigned short s_adj[1024 * 4];
  __shared__ unsigned char  s_deg[1024];
  __shared__ unsigned short s_bfs[1024];
  __shared__ short          s_parof[1024];
  __shared__ unsigned short s_o2b[1024];
  __shared__ unsigned short s_cur[1024];
  __shared__ unsigned short s_nxt[1024];
  __shared__ unsigned short s_off[1025];
  __shared__ unsigned short s_loff2[1026];
  __shared__ unsigned long long s_rootkey;
  __shared__ int s_ncomp, s_cursz, s_bfscnt, s_nextsz, s_nlvl;

  int b = blockIdx.x; int tid = threadIdx.x;
  const float* feats = ws + O_FEATS + (size_t)b * NP * DFEAT;

  // norms + fused r_sem (one pass over the thread's feats row) + defensive init
  {
    const float4* f4 = (const float4*)(feats + (size_t)tid * 256);
    const float4* g4 = (const float4*)(ws + O_GPROJ + b * 256);
    float d = 0.f, gdot = 0.f;
    for (int k = 0; k < 64; k++){
      float4 q = f4[k]; float4 g = g4[k];
      d += q.x*q.x + q.y*q.y + q.z*q.z + q.w*q.w;
      gdot += q.x*g.x + q.y*g.y + q.z*g.z + q.w*g.w;
    }
    s_ninv[tid] = 1.f / fmaxf(sqrtf(d), 1e-12f);
    float r = 1.f / (1.f + expf(-gdot * (1.f / 16.f)));
    s_r[tid] = r;
    ws[O_RSEM + b * NP + tid] = r;      // k_xdelta consumes this
    s_comp[tid] = tid;
    s_deg[tid] = 0;
    s_bfs[tid] = (unsigned short)tid;
    s_o2b[tid] = (unsigned short)tid;
    s_parof[tid] = -1;
  }
  for (int e = tid; e < NEDGE; e += 1024) s_mst[e] = 0;
  __syncthreads();

  // edge weights
  for (int e = tid; e < NEDGE; e += 1024){
    int u, v; edge_uv(e, u, v);
    const float4* fu = (const float4*)(feats + (size_t)u * 256);
    const float4* fv = (const float4*)(feats + (size_t)v * 256);
    float d = 0.f;
    for (int k = 0; k < 64; k++){ float4 a = fu[k], c = fv[k]; d += a.x*c.x + a.y*c.y + a.z*c.z + a.w*c.w; }
    float cosv = d * s_ninv[u] * s_ninv[v];
    s_w[e] = (1.f - s_r[u]) * (1.f - s_r[v]) * (-cosv) + 1e-6f;
  }
  __syncthreads();

  // Boruvka rounds
  for (int round = 0; round < 12; round++){
    s_best[tid] = ~0ull;
    __syncthreads();
    for (int e = tid; e < NEDGE; e += 1024){
      int u, v; edge_uv(e, u, v);
      int cu = s_comp[u], cv = s_comp[v];
      if (cu != cv){
        unsigned long long key = (((unsigned long long)f2sort(s_w[e])) << 32) | (unsigned int)e;
        atomicMin(&s_best[cu], key);
        atomicMin(&s_best[cv], key);
      }
    }
    __syncthreads();
    int l = tid;
    if (s_comp[tid] == tid && s_best[tid] != ~0ull){
      int e = (int)(s_best[tid] & 0xffffffffu);
      int u, v; edge_uv(e, u, v);
      s_mst[e] = 1;
      int cu = s_comp[u], cv = s_comp[v];
      l = (cu == tid) ? cv : cu;
    }
    s_link[tid] = l;
    __syncthreads();
    if (l != tid && s_link[l] == tid && tid < l) s_link[tid] = tid; // break 2-cycles
    __syncthreads();
    for (int it = 0; it < 10; it++){      // pointer jumping (double-buffered)
      int x = s_link[tid]; s_link2[tid] = s_link[x];
      __syncthreads();
      s_link[tid] = s_link2[tid];
      __syncthreads();
    }
    s_comp[tid] = s_link[s_comp[tid]];
    if (tid == 0) s_ncomp = 0;
    __syncthreads();
    if (s_comp[tid] == tid) atomicAdd(&s_ncomp, 1);
    __syncthreads();
    if (s_ncomp == 1) break;
    __syncthreads();
  }
  __syncthreads();

  // weight-ordered adjacency (== Kruskal insertion order for unique MST)
  {
    int v = tid; int i = v >> 5, j = v & 31;
    float wloc[4]; int nloc[4]; int d = 0;
    if (j > 0){ int e = (i < 31) ? (i * 63 + 2 * (j - 1)) : (1953 + (j - 1));
      if (s_mst[e]){ wloc[d] = s_w[e]; nloc[d] = v - 1; d++; } }
    if (j < 31){ int e = (i < 31) ? (i * 63 + 2 * j) : (1953 + j);
      if (s_mst[e]){ wloc[d] = s_w[e]; nloc[d] = v + 1; d++; } }
    if (i > 0){ int e = (i - 1) * 63 + ((j < 31) ? (2 * j + 1) : 62);
      if (s_mst[e]){ wloc[d] = s_w[e]; nloc[d] = v - 32; d++; } }
    if (i < 31){ int e = i * 63 + ((j < 31) ? (2 * j + 1) : 62);
      if (s_mst[e]){ wloc[d] = s_w[e]; nloc[d] = v + 32; d++; } }
    for (int a = 1; a < d; a++){
      float wv = wloc[a]; int nv = nloc[a]; int c = a - 1;
      while (c >= 0 && wloc[c] > wv){ wloc[c+1] = wloc[c]; nloc[c+1] = nloc[c]; c--; }
      wloc[c+1] = wv; nloc[c+1] = nv;
    }
    s_deg[v] = (unsigned char)d;
    for (int a = 0; a < d; a++) s_adj[v * 4 + a] = (unsigned short)nloc[a];
  }
  // root = argmax r (first index on ties)
  if (tid == 0) s_rootkey = 0ull;
  __syncthreads();
  {
    unsigned long long key = (((unsigned long long)f2sort(s_r[tid])) << 32) | (unsigned int)(1023 - tid);
    atomicMax(&s_rootkey, key);
  }
  __syncthreads();
  int root = 1023 - (int)(s_rootkey & 0xffffffffu);

  // level-parallel tree BFS (records level offsets for k_scan)
  if (tid == 0){
    s_bfs[0] = (unsigned short)root; s_o2b[root] = 0; s_parof[root] = -1;
    s_cur[0] = (unsigned short)root; s_cursz = 1; s_bfscnt = 1; s_nlvl = 0;
  }
  __syncthreads();
  for (int lev = 0; lev < 1024; lev++){
    int csz = s_cursz;
    if (csz <= 0) break;
    // wave-parallel exclusive scan of child counts
    if (tid < 64){
      int runbase = 0;
      for (int t0 = 0; t0 < csz; t0 += 64){
        int t = t0 + tid;
        int cnt = 0;
        if (t < csz){
          int n = s_cur[t];
          cnt = (int)s_deg[n] - (s_parof[n] >= 0 ? 1 : 0);
        }
        int v = cnt;
        #pragma unroll
        for (int off = 1; off < 64; off <<= 1){
          int u2 = __shfl_up(v, off);
          if (tid >= off) v += u2;
        }
        if (t < csz) s_off[t] = (unsigned short)(runbase + v - cnt);
        runbase += __shfl(v, 63);
      }
      if (tid == 0){
        if (s_nlvl < 1025){ s_loff2[s_nlvl] = (unsigned short)(s_bfscnt - csz); }
        s_nlvl++;
        s_nextsz = runbase;
      }
    }
    __syncthreads();
    if (tid < csz){
      int n = s_cur[tid]; int base = s_off[tid]; int k = 0;
      int pn = s_parof[n]; int dg = s_deg[n];
      for (int a = 0; a < dg; a++){
        int c = s_adj[n * 4 + a];
        if (c == pn) continue;
        s_parof[c] = (short)n;
        if (base + k < 1024) s_nxt[base + k] = (unsigned short)c;
        int pos = s_bfscnt + base + k;
        if (pos < 1024){
          s_bfs[pos] = (unsigned short)c;
          s_o2b[c] = (unsigned short)pos;
        }
        k++;
      }
    }
    __syncthreads();
    if (tid == 0){ s_bfscnt += s_nextsz; s_cursz = (s_nextsz > 1024) ? 1024 : s_nextsz; }
    __syncthreads();
    if (tid < s_cursz) s_cur[tid] = s_nxt[tid];
    __syncthreads();
  }
  __syncthreads();

  int* BFSo = (int*)(ws + O_BFS);
  int* PARo = (int*)(ws + O_PAR);
  {
    int node = s_bfs[tid] & 1023;
    BFSo[b * 1024 + tid] = node;
    int p = s_parof[node];
    PARo[b * 1024 + tid] = (p < 0) ? -1 : (int)(s_o2b[p] & 1023);
  }
  // export level table: [nlvl, loff[0..nlvl]] (loff[nlvl] = NP)
  {
    int* LVLo = (int*)(ws + O_LVL) + b * 1040;
    int nl = s_nlvl; if (nl > 1024) nl = 1024;
    if (tid == 0){ LVLo[0] = nl; LVLo[1 + nl] = NP; }
    if (tid < nl) LVLo[1 + tid] = (int)s_loff2[tid];
  }
}

// ---------------- K4: X, delta, Bp, Cp (k-major coalesced weight reads) --------------
__global__ __launch_bounds__(256) void k_xdelta(float* __restrict__ ws)
{
  __shared__ float xs[256];
  int blk = blockIdx.x; int b = blk >> 10, i = blk & 1023; int df = threadIdx.x;
  const int* BFSo = (const int*)(ws + O_BFS);
  int node = BFSo[b * 1024 + i] & 1023;
  float rs = ws[O_RSEM + b * 1024 + node];
  float xv = ws[O_FEATS + ((size_t)(b * 1024 + node)) * 256 + df] + rs * ws[O_GPRIM + b * 256 + df];
  xs[df] = xv;
  ws[O_X + ((size_t)(b * 1024 + i)) * 256 + df] = xv;
  __syncthreads();
  {
    const float* WT = ws + O_WDW;
    float z = ws[O_WDB + df];
    #pragma unroll 8
    for (int k = 0; k < 256; k++)
      z += WT[(size_t)k * 256 + df] * xs[k];
    float sp = fmaxf(z, 0.f) + log1pf(expf(-fabsf(z)));
    ws[O_DELTA + ((size_t)(b * 1024 + i)) * 256 + df] = sp * (1.f + 2.f * rs);
  }
  if (df < 32){
    int s = df & 15;
    const float* WT = ws + ((df < 16) ? O_BWO : O_CWO);   // [k][s]
    float a = ws[((df < 16) ? O_BBO : O_CBO) + s];
    #pragma unroll 8
    for (int k = 0; k < 256; k++) a += WT[k * 16 + s] * xs[k];
    ws[((df < 16) ? O_BP : O_CP) + (size_t)(b * 1024 + i) * 16 + s] = a;
  }
}

// ---------------- K5: tree scan, LEVEL-PARALLEL (R14) --------------------------------
// All nodes within a BFS level are independent (parents in the previous level).
// One wave = 4 nodes x 16 states per step; per-level single-wave barrier (cheap).
// Serial chain drops from 1024 steps to sum(ceil(level/4)) ~ 256 + depth*latency.
__global__ __launch_bounds__(64) void k_scan(float* __restrict__ ws)
{
  __shared__ float h[NP * DSTATE];   // 64 KB: h[pos][s]
  __shared__ float xs[NP];
  __shared__ float ds[NP];
  __shared__ int   par_s[NP];
  __shared__ int   bfs_s[NP];
  int blk = blockIdx.x; int b = blk >> 8, f = blk & 255;
  int lane = threadIdx.x;
  int g = lane >> 4, s = lane & 15;
  const int* PARo = (const int*)(ws + O_PAR);
  const int* BFSo = (const int*)(ws + O_BFS);
  const int* LVLo = (const int*)(ws + O_LVL) + b * 1040;
  for (int i = lane; i < NP; i += 64){
    xs[i] = ws[O_X     + ((size_t)(b * NP + i)) * DFEAT + f];
    ds[i] = ws[O_DELTA + ((size_t)(b * NP + i)) * DFEAT + f];
    par_s[i] = PARo[b * NP + i];
    bfs_s[i] = BFSo[b * NP + i] & 1023;
  }
  __syncthreads();

  int nlvl = LVLo[0];
  bool degen = (nlvl < 1 || nlvl > NP);
  if (degen) nlvl = NP;               // fallback: one node per level == serial order

  float Aln = ws[O_AF + f * 16 + s];
  float Dv  = ws[O_DD + f];
  const float* Bp = ws + O_BP + (size_t)b * NP * DSTATE;
  const float* Cp = ws + O_CP + (size_t)b * NP * DSTATE;
  float* Yr = ws + O_YR + (size_t)b * NP * DFEAT;

  for (int l = 0; l < nlvl; l++){
    int o0, o1;
    if (degen){ o0 = l; o1 = l + 1; }
    else {
      o0 = LVLo[1 + l]; o1 = LVLo[2 + l];
      o0 = (o0 < 0) ? 0 : ((o0 > NP) ? NP : o0);
      o1 = (o1 < o0) ? o0 : ((o1 > NP) ? NP : o1);
    }
    for (int i = o0 + g; i < o1; i += 4){
      int p = par_s[i];
      float d = ds[i], x = xs[i];
      float hp = (p >= 0 && p < i) ? h[p * 16 + s] : 0.f;
      float hn = expf(d * Aln) * hp + d * Bp[i * 16 + s] * x;
      h[i * 16 + s] = hn;
      float t = hn * Cp[i * 16 + s];
      t += __shfl_xor(t, 1); t += __shfl_xor(t, 2);
      t += __shfl_xor(t, 4); t += __shfl_xor(t, 8);
      if (s == 0) Yr[(size_t)bfs_s[i] * DFEAT + f] = t + Dv * x;
    }
    __syncthreads();   // single-wave barrier: cheap; orders level l writes vs l+1 reads
  }
}

// ---------------- K6: out GEMM (k-major coalesced) + LayerNorm -> out dtype ----------
__global__ __launch_bounds__(256) void k_outln(const float* __restrict__ ws,
                                               void* __restrict__ out)
{
  __shared__ float yl[256];
  __shared__ float red[8];
  const int F = ((const int*)(ws + O_FLAG))[0];
  int blk = blockIdx.x; int b = blk >> 10, p = blk & 1023; int df = threadIdx.x;
  yl[df] = ws[O_YR + ((size_t)(b * 1024 + p)) * 256 + df];
  __syncthreads();
  const float* OT = ws + O_OW;   // [k][df]
  float a = ws[O_OB + df];
  #pragma unroll 8
  for (int k = 0; k < 256; k++)
    a += OT[(size_t)k * 256 + df] * yl[k];
  int lane = df & 63, wid = df >> 6;
  float t = a;
  t += __shfl_xor(t, 1); t += __shfl_xor(t, 2);  t += __shfl_xor(t, 4);
  t += __shfl_xor(t, 8); t += __shfl_xor(t, 16); t += __shfl_xor(t, 32);
  if (lane == 0) red[wid] = t;
  __syncthreads();
  float mu = (red[0] + red[1] + red[2] + red[3]) * (1.f / 256.f);
  float dv = a - mu;
  float t2 = dv * dv;
  t2 += __shfl_xor(t2, 1); t2 += __shfl_xor(t2, 2);  t2 += __shfl_xor(t2, 4);
  t2 += __shfl_xor(t2, 8); t2 += __shfl_xor(t2, 16); t2 += __shfl_xor(t2, 32);
  if (lane == 0) red[4 + wid] = t2;
  __syncthreads();
  float var = (red[4] + red[5] + red[6] + red[7]) * (1.f / 256.f);
  float o = ws[O_LNG + df] * dv / sqrtf(var + 1e-5f) + ws[O_LNB + df];
  size_t idx = ((size_t)(b * 1024 + p)) * 256 + df;
  if (F) ((ushortb*)out)[idx] = f2bf(o);
  else   ((float*)out)[idx]   = o;
}

// ---------------- launch ----------------
extern "C" void kernel_launch(void* const* d_in, const int* in_sizes, int n_in,
                              void* d_out, int out_size, void* d_ws, size_t ws_size,
                              hipStream_t stream)
{
  (void)in_sizes; (void)n_in; (void)out_size; (void)ws_size;
  const void* img   = d_in[0];
  const void* lang  = d_in[1];
  const void* c1w   = d_in[2];
  const void* c1b   = d_in[3];
  const void* c2w   = d_in[4];
  const void* c2b   = d_in[5];
  const void* fcw   = d_in[6];
  const void* fcb   = d_in[7];
  const void* wgate = d_in[8];
  const void* wgp   = d_in[9];
  const void* alog  = d_in[10];
  const void* dvec  = d_in[11];
  const void* bw    = d_in[12];
  const void* bb    = d_in[13];
  const void* cw    = d_in[14];
  const void* cb    = d_in[15];
  const void* wdw   = d_in[16];
  const void* wdb   = d_in[17];
  const void* ow    = d_in[18];
  const void* ob    = d_in[19];
  const void* lng   = d_in[20];
  const void* lnb   = d_in[21];
  float* ws = (float*)d_ws;

  k_sniff<<<1, 256, 0, stream>>>(img, ws);
  k_convert<<<990 + 2048, 256, 0, stream>>>(c1w, c1b, c2w, c2b, fcw, fcb, alog, dvec,
                                            bw, bb, cw, cb, wdw, wdb, ow, ob, lng, lnb, ws);
  k_patch<<<2048, 512, 0, stream>>>(img, ws, ws + O_FEATS);
  k_gmm<<<256, 256, 0, stream>>>(lang, wgate, wgp, ws);
  k_struct<<<2, 1024, 0, stream>>>(ws);
  k_xdelta<<<2048, 256, 0, stream>>>(ws);
  k_scan<<<NB * DFEAT, 64, 0, stream>>>(ws);
  k_outln<<<2048, 256, 0, stream>>>(ws, d_out);
}

// Round 15
// 1873.507 us; speedup vs baseline: 1.7163x; 1.0641x over previous
//
#include <hip/hip_runtime.h>
#include <cstddef>
#include <cstdint>

// ---------------- constants ----------------
#define NB    2
#define NP    1024    // patches per image
#define DFEAT 256
#define DSTATE 16
#define NEDGE 1984    // grid edges: 31*63 + 31

typedef unsigned short ushortb;

// ---------------- helpers ----------------
__device__ __forceinline__ float bf2f(unsigned short u){
  union { unsigned int i; float f; } c; c.i = ((unsigned int)u) << 16; return c.f;
}
__device__ __forceinline__ unsigned short f2bf(float f){
  union { float f; unsigned int i; } c; c.f = f;
  unsigned int u = c.i;
  unsigned int r = (u + 0x7fffu + ((u >> 16) & 1u)) >> 16;
  return (unsigned short)r;
}
// dtype-generic input load: isbf ? bf16[i] : fp32[i]
__device__ __forceinline__ float ldin(const void* p, size_t i, int isbf){
  return isbf ? bf2f(((const ushortb*)p)[i]) : ((const float*)p)[i];
}
__device__ __forceinline__ float gelu_f(float x){
  return 0.5f * x * (1.0f + erff(x * 0.70710678118654752f));
}
__device__ __forceinline__ unsigned int f2sort(float f){
  union { float f; unsigned int i; } c; c.f = f;
  return (c.i & 0x80000000u) ? ~c.i : (c.i | 0x80000000u);
}

// ---------------- ws layout (float element offsets) ----------------
constexpr size_t AL(size_t x){ return (x + 63) & ~(size_t)63; }
constexpr size_t O_W1    = 0;                       // 1728  conv1 w fp32
constexpr size_t O_B1    = AL(O_W1 + 1728);         // 64
constexpr size_t O_W2    = AL(O_B1 + 64);           // 73728 conv2 w fp32, layout [g][ic][ocl][9]
constexpr size_t O_B2    = AL(O_W2 + 73728);        // 128
constexpr size_t O_FCW   = AL(O_B2 + 128);          // 32768 [df][128]
constexpr size_t O_FCB   = AL(O_FCW + 32768);       // 256
constexpr size_t O_WDW   = AL(O_FCB + 256);         // 65536 TRANSPOSED [k][df]
constexpr size_t O_WDB   = AL(O_WDW + 65536);       // 256
constexpr size_t O_BWO   = AL(O_WDB + 256);         // 4096 TRANSPOSED [k][s]
constexpr size_t O_BBO   = AL(O_BWO + 4096);        // 16
constexpr size_t O_CWO   = AL(O_BBO + 16);          // 4096 TRANSPOSED [k][s]
constexpr size_t O_CBO   = AL(O_CWO + 4096);        // 16
constexpr size_t O_OW    = AL(O_CBO + 16);          // 65536 TRANSPOSED [k][df]
constexpr size_t O_OB    = AL(O_OW + 65536);        // 256
constexpr size_t O_AF    = AL(O_OB + 256);          // 4096  A = -exp(A_log), [f][s]
constexpr size_t O_DD    = AL(O_AF + 4096);         // 256
constexpr size_t O_LNG   = AL(O_DD + 256);          // 256
constexpr size_t O_LNB   = AL(O_LNG + 256);         // 256
constexpr size_t O_FEATS = AL(O_LNB + 256);         // 2*1024*256
constexpr size_t O_GPROJ = AL(O_FEATS + (size_t)NB*NP*DFEAT); // 512
constexpr size_t O_GPRIM = AL(O_GPROJ + NB*DFEAT);  // 512
constexpr size_t O_RSEM  = AL(O_GPRIM + NB*DFEAT);  // 2048
constexpr size_t O_BFS   = AL(O_RSEM + NB*NP);      // 2048 (int)
constexpr size_t O_PAR   = AL(O_BFS + NB*NP);       // 2048 (int)
constexpr size_t O_X     = AL(O_PAR + NB*NP);       // 2*1024*256
constexpr size_t O_DELTA = AL(O_X + (size_t)NB*NP*DFEAT);
constexpr size_t O_BP    = AL(O_DELTA + (size_t)NB*NP*DFEAT); // 2*1024*16
constexpr size_t O_CP    = AL(O_BP + NB*NP*DSTATE);
constexpr size_t O_YR    = AL(O_CP + NB*NP*DSTATE); // 2*1024*256
constexpr size_t O_FLAG  = AL(O_YR + (size_t)NB*NP*DFEAT);    // 1 int: is-bf16 flag
constexpr size_t O_LVL   = AL(O_FLAG + 64);         // NB*1040 ints: [nlvl, loff[0..nlvl]]

// ---------------- K-1: sniff input dtype (bf16 vs fp32) from images buffer -----------
__global__ __launch_bounds__(256) void k_sniff(const void* img, float* ws)
{
  __shared__ int cnt;
  int tid = threadIdx.x;
  if (tid == 0) cnt = 0;
  __syncthreads();
  const ushortb* u = (const ushortb*)img;
  int local = 0;
  for (int k = 0; k < 16; k++){
    unsigned short v = u[tid * 16 + k];
    if (v == 0 || v == 0x8000u){ local++; continue; }
    float f = fabsf(bf2f(v));
    if (f >= 1e-8f && f <= 64.f) local++;    // plausible N(0,1) bf16
  }
  atomicAdd(&cnt, local);
  __syncthreads();
  if (tid == 0) ((int*)(ws + O_FLAG))[0] = (cnt >= 3900) ? 1 : 0;  // >=95% plausible
}

// ---------------- K0: convert weights + zero YR + g_proj/g_prime (all fused) ---------
// blocks [0,990): weight convert; [990,3038): YR zero; [3038,3294): gmm rows.
__global__ __launch_bounds__(256) void k_convert(const void* c1w, const void* c1b, const void* c2w,
                          const void* c2b, const void* fcw, const void* fcb,
                          const void* alog, const void* dvec,
                          const void* bw, const void* bb, const void* cw, const void* cb,
                          const void* wdw, const void* wdb,
                          const void* ow, const void* ob,
                          const void* lng, const void* lnb,
                          const void* lang, const void* wgate, const void* wgp,
                          float* ws)
{
  const int F = ((const int*)(ws + O_FLAG))[0];
  if (blockIdx.x >= 3038){  // gmm branch: wave-per-row coalesced dual GEMV
    int row = (blockIdx.x - 3038) * 4 + (threadIdx.x >> 6);
    int lane = threadIdx.x & 63;
    int mat = row >> 9;
    int b   = (row >> 8) & 1;
    int df  = row & 255;
    const void* W = mat ? wgp : wgate;
    float s = 0.f;
    for (int k = lane; k < 896; k += 64)
      s += ldin(lang, (size_t)b * 896 + k, F) * ldin(W, (size_t)df * 896 + k, F);
    s += __shfl_xor(s, 1);  s += __shfl_xor(s, 2);  s += __shfl_xor(s, 4);
    s += __shfl_xor(s, 8);  s += __shfl_xor(s, 16); s += __shfl_xor(s, 32);
    if (lane == 0) ws[(mat ? O_GPRIM : O_GPROJ) + b * 256 + df] = s;
    return;
  }
  if (blockIdx.x >= 990){   // init branch: zero YR
    size_t i2 = (size_t)(blockIdx.x - 990) * 256 + threadIdx.x;
    if (i2 < (size_t)NB * NP * DFEAT) ws[O_YR + i2] = 0.f;
    return;
  }
  int i = blockIdx.x * 256 + threadIdx.x;
  if (i < 1728){ ws[O_W1 + i] = ldin(c1w, i, F); return; } i -= 1728;
  if (i < 64){ ws[O_B1 + i] = ldin(c1b, i, F); return; } i -= 64;
  if (i < 73728){
    // dst layout [g=0..15][ic=0..63][ocl=0..7][9]: i = ((g*64+ic)*8+ocl)*9 + t
    int g = i / 4608; int r = i - g * 4608;
    int ic = r / 72;  int r2 = r - ic * 72;
    int ocl = r2 / 9; int t = r2 - ocl * 9;
    int oc = (g >> 3) * 64 + (g & 7) * 8 + ocl;
    ws[O_W2 + i] = ldin(c2w, (size_t)(oc * 64 + ic) * 9 + t, F); return;
  } i -= 73728;
  if (i < 128){ ws[O_B2 + i] = ldin(c2b, i, F); return; } i -= 128;
  if (i < 32768){ ws[O_FCW + i] = ldin(fcw, i, F); return; } i -= 32768;
  if (i < 256){ ws[O_FCB + i] = ldin(fcb, i, F); return; } i -= 256;
  if (i < 65536){  // WDW transposed: dst[k*256+df] = src[df*256+k]
    int k = i >> 8, df = i & 255;
    ws[O_WDW + i] = ldin(wdw, (size_t)df * 256 + k, F); return;
  } i -= 65536;
  if (i < 256){ ws[O_WDB + i] = ldin(wdb, i, F); return; } i -= 256;
  if (i < 4096){   // B_w transposed: dst[k*16+s] = src[s*256+k]
    int k = i >> 4, s = i & 15;
    ws[O_BWO + i] = ldin(bw, (size_t)s * 256 + k, F); return;
  } i -= 4096;
  if (i < 16){ ws[O_BBO + i] = ldin(bb, i, F); return; } i -= 16;
  if (i < 4096){   // C_w transposed
    int k = i >> 4, s = i & 15;
    ws[O_CWO + i] = ldin(cw, (size_t)s * 256 + k, F); return;
  } i -= 4096;
  if (i < 16){ ws[O_CBO + i] = ldin(cb, i, F); return; } i -= 16;
  if (i < 65536){  // out_w transposed: dst[k*256+df] = src[df*256+k]
    int k = i >> 8, df = i & 255;
    ws[O_OW + i] = ldin(ow, (size_t)df * 256 + k, F); return;
  } i -= 65536;
  if (i < 256){ ws[O_OB + i] = ldin(ob, i, F); return; } i -= 256;
  if (i < 4096){ ws[O_AF + i] = -expf(ldin(alog, i, F)); return; } i -= 4096;
  if (i < 256){ ws[O_DD + i] = ldin(dvec, i, F); return; } i -= 256;
  if (i < 256){ ws[O_LNG + i] = ldin(lng, i, F); return; } i -= 256;
  if (i < 256){ ws[O_LNB + i] = ldin(lnb, i, F); return; }
}

// ---------------- K1: per-patch conv1+gelu+conv2+gelu+pool+fc (R8 verbatim) ----------
__global__ __launch_bounds__(512, 4) void k_patch(const void* __restrict__ img,
                                                  const float* __restrict__ ws,
                                                  float* __restrict__ feats)
{
  __shared__ float sm[64 * 256];  // 64KB: h1 [64 ic][256 px]
  __shared__ float timg[768];     // 3KB input tile [3 c][256 px]
  __shared__ float pool[128];     // pooled sums per oc
  __shared__ float pm[128];       // pooled mean
  const int F = ((const int*)(ws + O_FLAG))[0];
  const float* W1 = ws + O_W1;  const float* B1 = ws + O_B1;
  const float* W2 = ws + O_W2;  const float* B2 = ws + O_B2;
  const float* FCW = ws + O_FCW; const float* FCB = ws + O_FCB;

  int blk = blockIdx.x; int b = blk >> 10; int pidx = blk & 1023;
  int ph = pidx >> 5, pw = pidx & 31;
  int tid = threadIdx.x;

  // stage input tile (16x16x3) into LDS
  if (tid < 256){
    int y = tid >> 4, x = tid & 15;
    #pragma unroll
    for (int c = 0; c < 3; c++)
      timg[c * 256 + tid] =
        ldin(img, (((size_t)b * 3 + c) * 512 + (ph * 16 + y)) * 512 + (pw * 16 + x), F);
  }
  __syncthreads();

  // conv1 + gelu -> sm: thread = (pixel p, oc-group og of 32)
  {
    int p = tid & 255, og = tid >> 8;
    int ii = p >> 4, jj = p & 15;
    float pin[27];
    #pragma unroll
    for (int c = 0; c < 3; c++)
      #pragma unroll
      for (int dy = 0; dy < 3; dy++)
        #pragma unroll
        for (int dx = 0; dx < 3; dx++){
          int y = ii + dy - 1, x = jj + dx - 1;
          bool ok = (y >= 0 && y < 16 && x >= 0 && x < 16);
          pin[c * 9 + dy * 3 + dx] = ok ? timg[c * 256 + y * 16 + x] : 0.f;
        }
    for (int o = 0; o < 32; o++){
      int oc = og * 32 + o;
      float a = B1[oc];
      #pragma unroll
      for (int t = 0; t < 27; t++) a += W1[oc * 27 + t] * pin[t];
      sm[oc * 256 + p] = gelu_f(a);
    }
  }
  __syncthreads();

  // conv2: wave w (0..7) x half h (0..1) -> 8 oc; lane = 4 consecutive px in a row
  int wv = tid >> 6, ln = tid & 63;
  int row = ln >> 2, cg = ln & 3;
  int c0 = cg * 4;   // first pixel col of this lane's group

  for (int h = 0; h < 2; h++){
    int oc0 = h * 64 + wv * 8;
    float acc[4][8];
    #pragma unroll
    for (int o = 0; o < 8; o++){
      float bz = B2[oc0 + o];
      #pragma unroll
      for (int j = 0; j < 4; j++) acc[j][o] = bz;
    }
    const float* wg = W2 + ((size_t)(h * 8 + wv)) * 4608;   // [ic][ocl][9]
    for (int ic = 0; ic < 64; ic++){
      float win[3][6];
      #pragma unroll
      for (int r = 0; r < 3; r++){
        int y = row - 1 + r;
        bool yok = (y >= 0 && y < 16);
        #pragma unroll
        for (int cc = 0; cc < 6; cc++){
          int x = c0 - 1 + cc;
          win[r][cc] = (yok && x >= 0 && x < 16) ? sm[ic * 256 + y * 16 + x] : 0.f;
        }
      }
      const float* wp = wg + (size_t)ic * 72;   // 72 contiguous wave-uniform floats
      #pragma unroll
      for (int o = 0; o < 8; o++){
        #pragma unroll
        for (int t9 = 0; t9 < 9; t9++){
          int dy = t9 / 3, dx = t9 - dy * 3;
          float wvv = wp[o * 9 + t9];
          #pragma unroll
          for (int j = 0; j < 4; j++)
            acc[j][o] += wvv * win[dy][j + dx];
        }
      }
    }
    // gelu + pool: lane sums its 4 px, wave-reduce over 64 lanes (256 px total)
    #pragma unroll
    for (int o = 0; o < 8; o++){
      float g = gelu_f(acc[0][o]) + gelu_f(acc[1][o]) + gelu_f(acc[2][o]) + gelu_f(acc[3][o]);
      g += __shfl_xor(g, 1);  g += __shfl_xor(g, 2);  g += __shfl_xor(g, 4);
      g += __shfl_xor(g, 8);  g += __shfl_xor(g, 16); g += __shfl_xor(g, 32);
      if (ln == 0) pool[oc0 + o] = g;   // waves own disjoint oc, no merge needed
    }
  }
  __syncthreads();
  if (tid < 128) pm[tid] = pool[tid] * (1.f / 256.f);
  __syncthreads();

  // fc 128 -> 256 (threads 0..255)
  if (tid < 256){
    int df = tid;
    float s = FCB[df];
    const float* wrow = FCW + (size_t)df * 128;
    #pragma unroll
    for (int k = 0; k < 128; k += 4)
      s += wrow[k] * pm[k] + wrow[k + 1] * pm[k + 1]
         + wrow[k + 2] * pm[k + 2] + wrow[k + 3] * pm[k + 3];
    feats[((size_t)(b * 1024 + pidx)) * 256 + df] = s;
  }
}

// ---------------- K3: structure (rsem fused + Boruvka MST + adjacency + level BFS) ---
__device__ __forceinline__ void edge_uv(int e, int& u, int& v){
  if (e < 1953){
    int i = e / 63; int k = e - i * 63;
    if (k < 62){ int j = k >> 1; u = i * 32 + j; v = (k & 1) ? u + 32 : u + 1; }
    else { u = i * 32 + 31; v = u + 32; }
  } else { u = 31 * 32 + (e - 1953); v = u + 1; }
}

__global__ __launch_bounds__(1024) void k_struct(float* __restrict__ ws)
{
  __shared__ float s_ninv[1024];
  __shared__ float s_w[NEDGE];
  __shared__ float s_r[1024];
  __shared__ int   s_comp[1024];
  __shared__ int   s_link[1024];
  __shared__ int   s_link2[1024];
  __shared__ unsigned long long s_best[1024];
  __shared__ unsigned char  s_mst[NEDGE];
  __shared__ unsigned short s_adj[1024 * 4];
  __shared__ unsigned char  s_deg[1024];
  __shared__ unsigned short s_bfs[1024];
  __shared__ short          s_parof[1024];
  __shared__ unsigned short s_o2b[1024];
  __shared__ unsigned short s_cur[1024];
  __shared__ unsigned short s_nxt[1024];
  __shared__ unsigned short s_off[1025];
  __shared__ unsigned short s_loff2[1026];
  __shared__ unsigned long long s_rootkey;
  __shared__ int s_ncomp, s_cursz, s_bfscnt, s_nextsz, s_nlvl;

  int b = blockIdx.x; int tid = threadIdx.x;
  const float* feats = ws + O_FEATS + (size_t)b * NP * DFEAT;

  // norms + fused r_sem + defensive init
  {
    const float4* f4 = (const float4*)(feats + (size_t)tid * 256);
    const float4* g4 = (const float4*)(ws + O_GPROJ + b * 256);
    float d = 0.f, gdot = 0.f;
    for (int k = 0; k < 64; k++){
      float4 q = f4[k]; float4 g = g4[k];
      d += q.x*q.x + q.y*q.y + q.z*q.z + q.w*q.w;
      gdot += q.x*g.x + q.y*g.y + q.z*g.z + q.w*g.w;
    }
    s_ninv[tid] = 1.f / fmaxf(sqrtf(d), 1e-12f);
    float r = 1.f / (1.f + expf(-gdot * (1.f / 16.f)));
    s_r[tid] = r;
    ws[O_RSEM + b * NP + tid] = r;      // k_xdelta consumes this
    s_comp[tid] = tid;
    s_deg[tid] = 0;
    s_bfs[tid] = (unsigned short)tid;
    s_o2b[tid] = (unsigned short)tid;
    s_parof[tid] = -1;
  }
  for (int e = tid; e < NEDGE; e += 1024) s_mst[e] = 0;
  __syncthreads();

  // edge weights
  for (int e = tid; e < NEDGE; e += 1024){
    int u, v; edge_uv(e, u, v);
    const float4* fu = (const float4*)(feats + (size_t)u * 256);
    const float4* fv = (const float4*)(feats + (size_t)v * 256);
    float d = 0.f;
    for (int k = 0; k < 64; k++){ float4 a = fu[k], c = fv[k]; d += a.x*c.x + a.y*c.y + a.z*c.z + a.w*c.w; }
    float cosv = d * s_ninv[u] * s_ninv[v];
    s_w[e] = (1.f - s_r[u]) * (1.f - s_r[v]) * (-cosv) + 1e-6f;
  }
  __syncthreads();

  // Boruvka rounds
  for (int round = 0; round < 12; round++){
    s_best[tid] = ~0ull;
    __syncthreads();
    for (int e = tid; e < NEDGE; e += 1024){
      int u, v; edge_uv(e, u, v);
      int cu = s_comp[u], cv = s_comp[v];
      if (cu != cv){
        unsigned long long key = (((unsigned long long)f2sort(s_w[e])) << 32) | (unsigned int)e;
        atomicMin(&s_best[cu], key);
        atomicMin(&s_best[cv], key);
      }
    }
    __syncthreads();
    int l = tid;
    if (s_comp[tid] == tid && s_best[tid] != ~0ull){
      int e = (int)(s_best[tid] & 0xffffffffu);
      int u, v; edge_uv(e, u, v);
      s_mst[e] = 1;
      int cu = s_comp[u], cv = s_comp[v];
      l = (cu == tid) ? cv : cu;
    }
    s_link[tid] = l;
    __syncthreads();
    if (l != tid && s_link[l] == tid && tid < l) s_link[tid] = tid; // break 2-cycles
    __syncthreads();
    for (int it = 0; it < 10; it++){      // pointer jumping (double-buffered)
      int x = s_link[tid]; s_link2[tid] = s_link[x];
      __syncthreads();
      s_link[tid] = s_link2[tid];
      __syncthreads();
    }
    s_comp[tid] = s_link[s_comp[tid]];
    if (tid == 0) s_ncomp = 0;
    __syncthreads();
    if (s_comp[tid] == tid) atomicAdd(&s_ncomp, 1);
    __syncthreads();
    if (s_ncomp == 1) break;
    __syncthreads();
  }
  __syncthreads();

  // weight-ordered adjacency (== Kruskal insertion order for unique MST)
  {
    int v = tid; int i = v >> 5, j = v & 31;
    float wloc[4]; int nloc[4]; int d = 0;
    if (j > 0){ int e = (i < 31) ? (i * 63 + 2 * (j - 1)) : (1953 + (j - 1));
      if (s_mst[e]){ wloc[d] = s_w[e]; nloc[d] = v - 1; d++; } }
    if (j < 31){ int e = (i < 31) ? (i * 63 + 2 * j) : (1953 + j);
      if (s_mst[e]){ wloc[d] = s_w[e]; nloc[d] = v + 1; d++; } }
    if (i > 0){ int e = (i - 1) * 63 + ((j < 31) ? (2 * j + 1) : 62);
      if (s_mst[e]){ wloc[d] = s_w[e]; nloc[d] = v - 32; d++; } }
    if (i < 31){ int e = i * 63 + ((j < 31) ? (2 * j + 1) : 62);
      if (s_mst[e]){ wloc[d] = s_w[e]; nloc[d] = v + 32; d++; } }
    for (int a = 1; a < d; a++){
      float wv = wloc[a]; int nv = nloc[a]; int c = a - 1;
      while (c >= 0 && wloc[c] > wv){ wloc[c+1] = wloc[c]; nloc[c+1] = nloc[c]; c--; }
      wloc[c+1] = wv; nloc[c+1] = nv;
    }
    s_deg[v] = (unsigned char)d;
    for (int a = 0; a < d; a++) s_adj[v * 4 + a] = (unsigned short)nloc[a];
  }
  // root = argmax r (first index on ties)
  if (tid == 0) s_rootkey = 0ull;
  __syncthreads();
  {
    unsigned long long key = (((unsigned long long)f2sort(s_r[tid])) << 32) | (unsigned int)(1023 - tid);
    atomicMax(&s_rootkey, key);
  }
  __syncthreads();
  int root = 1023 - (int)(s_rootkey & 0xffffffffu);

  // level-parallel tree BFS (records level offsets for k_scan)
  if (tid == 0){
    s_bfs[0] = (unsigned short)root; s_o2b[root] = 0; s_parof[root] = -1;
    s_cur[0] = (unsigned short)root; s_cursz = 1; s_bfscnt = 1; s_nlvl = 0;
  }
  __syncthreads();
  for (int lev = 0; lev < 1024; lev++){
    int csz = s_cursz;
    if (csz <= 0) break;
    // wave-parallel exclusive scan of child counts
    if (tid < 64){
      int runbase = 0;
      for (int t0 = 0; t0 < csz; t0 += 64){
        int t = t0 + tid;
        int cnt = 0;
        if (t < csz){
          int n = s_cur[t];
          cnt = (int)s_deg[n] - (s_parof[n] >= 0 ? 1 : 0);
        }
        int v = cnt;
        #pragma unroll
        for (int off = 1; off < 64; off <<= 1){
          int u2 = __shfl_up(v, off);
          if (tid >= off) v += u2;
        }
        if (t < csz) s_off[t] = (unsigned short)(runbase + v - cnt);
        runbase += __shfl(v, 63);
      }
      if (tid == 0){
        if (s_nlvl < 1025){ s_loff2[s_nlvl] = (unsigned short)(s_bfscnt - csz); }
        s_nlvl++;
        s_nextsz = runbase;
      }
    }
    __syncthreads();
    if (tid < csz){
      int n = s_cur[tid]; int base = s_off[tid]; int k = 0;
      int pn = s_parof[n]; int dg = s_deg[n];
      for (int a = 0; a < dg; a++){
        int c = s_adj[n * 4 + a];
        if (c == pn) continue;
        s_parof[c] = (short)n;
        if (base + k < 1024) s_nxt[base + k] = (unsigned short)c;
        int pos = s_bfscnt + base + k;
        if (pos < 1024){
          s_bfs[pos] = (unsigned short)c;
          s_o2b[c] = (unsigned short)pos;
        }
        k++;
      }
    }
    __syncthreads();
    if (tid == 0){ s_bfscnt += s_nextsz; s_cursz = (s_nextsz > 1024) ? 1024 : s_nextsz; }
    __syncthreads();
    if (tid < s_cursz) s_cur[tid] = s_nxt[tid];
    __syncthreads();
  }
  __syncthreads();

  int* BFSo = (int*)(ws + O_BFS);
  int* PARo = (int*)(ws + O_PAR);
  {
    int node = s_bfs[tid] & 1023;
    BFSo[b * 1024 + tid] = node;
    int p = s_parof[node];
    PARo[b * 1024 + tid] = (p < 0) ? -1 : (int)(s_o2b[p] & 1023);
  }
  // export level table: [nlvl, loff[0..nlvl]] (loff[nlvl] = NP)
  {
    int* LVLo = (int*)(ws + O_LVL) + b * 1040;
    int nl = s_nlvl; if (nl > 1024) nl = 1024;
    if (tid == 0){ LVLo[0] = nl; LVLo[1 + nl] = NP; }
    if (tid < nl) LVLo[1 + tid] = (int)s_loff2[tid];
  }
}

// ---------------- K4: X, delta, Bp, Cp (k-major coalesced weight reads) --------------
__global__ __launch_bounds__(256) void k_xdelta(float* __restrict__ ws)
{
  __shared__ float xs[256];
  int blk = blockIdx.x; int b = blk >> 10, i = blk & 1023; int df = threadIdx.x;
  const int* BFSo = (const int*)(ws + O_BFS);
  int node = BFSo[b * 1024 + i] & 1023;
  float rs = ws[O_RSEM + b * 1024 + node];
  float xv = ws[O_FEATS + ((size_t)(b * 1024 + node)) * 256 + df] + rs * ws[O_GPRIM + b * 256 + df];
  xs[df] = xv;
  ws[O_X + ((size_t)(b * 1024 + i)) * 256 + df] = xv;
  __syncthreads();
  {
    const float* WT = ws + O_WDW;
    float z = ws[O_WDB + df];
    #pragma unroll 8
    for (int k = 0; k < 256; k++)
      z += WT[(size_t)k * 256 + df] * xs[k];
    float sp = fmaxf(z, 0.f) + log1pf(expf(-fabsf(z)));
    ws[O_DELTA + ((size_t)(b * 1024 + i)) * 256 + df] = sp * (1.f + 2.f * rs);
  }
  if (df < 32){
    int s = df & 15;
    const float* WT = ws + ((df < 16) ? O_BWO : O_CWO);   // [k][s]
    float a = ws[((df < 16) ? O_BBO : O_CBO) + s];
    #pragma unroll 8
    for (int k = 0; k < 256; k++) a += WT[k * 16 + s] * xs[k];
    ws[((df < 16) ? O_BP : O_CP) + (size_t)(b * 1024 + i) * 16 + s] = a;
  }
}

// ---------------- K5: tree scan, LEVEL-PARALLEL, 256 threads (R15) -------------------
// 16 node-groups x 16 states per step (was 4); per-level 4-wave barrier.
__global__ __launch_bounds__(256) void k_scan(float* __restrict__ ws)
{
  __shared__ float h[NP * DSTATE];   // 64 KB: h[pos][s]
  __shared__ float xs[NP];
  __shared__ float ds[NP];
  __shared__ int   par_s[NP];
  __shared__ int   bfs_s[NP];
  int blk = blockIdx.x; int b = blk >> 8, f = blk & 255;
  int tid = threadIdx.x;
  int g = tid >> 4, s = tid & 15;
  const int* PARo = (const int*)(ws + O_PAR);
  const int* BFSo = (const int*)(ws + O_BFS);
  const int* LVLo = (const int*)(ws + O_LVL) + b * 1040;
  for (int i = tid; i < NP; i += 256){
    xs[i] = ws[O_X     + ((size_t)(b * NP + i)) * DFEAT + f];
    ds[i] = ws[O_DELTA + ((size_t)(b * NP + i)) * DFEAT + f];
    par_s[i] = PARo[b * NP + i];
    bfs_s[i] = BFSo[b * NP + i] & 1023;
  }
  __syncthreads();

  int nlvl = LVLo[0];
  bool degen = (nlvl < 1 || nlvl > NP);
  if (degen) nlvl = NP;               // fallback: one node per level == serial order

  float Aln = ws[O_AF + f * 16 + s];
  float Dv  = ws[O_DD + f];
  const float* Bp = ws + O_BP + (size_t)b * NP * DSTATE;
  const float* Cp = ws + O_CP + (size_t)b * NP * DSTATE;
  float* Yr = ws + O_YR + (size_t)b * NP * DFEAT;

  for (int l = 0; l < nlvl; l++){
    int o0, o1;
    if (degen){ o0 = l; o1 = l + 1; }
    else {
      o0 = LVLo[1 + l]; o1 = LVLo[2 + l];
      o0 = (o0 < 0) ? 0 : ((o0 > NP) ? NP : o0);
      o1 = (o1 < o0) ? o0 : ((o1 > NP) ? NP : o1);
    }
    for (int i = o0 + g; i < o1; i += 16){
      int p = par_s[i];
      float d = ds[i], x = xs[i];
      float hp = (p >= 0 && p < i) ? h[p * 16 + s] : 0.f;
      float hn = expf(d * Aln) * hp + d * Bp[i * 16 + s] * x;
      h[i * 16 + s] = hn;
      float t = hn * Cp[i * 16 + s];
      t += __shfl_xor(t, 1); t += __shfl_xor(t, 2);
      t += __shfl_xor(t, 4); t += __shfl_xor(t, 8);
      if (s == 0) Yr[(size_t)bfs_s[i] * DFEAT + f] = t + Dv * x;
    }
    __syncthreads();   // orders level l writes vs l+1 reads
  }
}

// ---------------- K6: out GEMM (k-major coalesced) + LayerNorm -> out dtype ----------
__global__ __launch_bounds__(256) void k_outln(const float* __restrict__ ws,
                                               void* __restrict__ out)
{
  __shared__ float yl[256];
  __shared__ float red[8];
  const int F = ((const int*)(ws + O_FLAG))[0];
  int blk = blockIdx.x; int b = blk >> 10, p = blk & 1023; int df = threadIdx.x;
  yl[df] = ws[O_YR + ((size_t)(b * 1024 + p)) * 256 + df];
  __syncthreads();
  const float* OT = ws + O_OW;   // [k][df]
  float a = ws[O_OB + df];
  #pragma unroll 8
  for (int k = 0; k < 256; k++)
    a += OT[(size_t)k * 256 + df] * yl[k];
  int lane = df & 63, wid = df >> 6;
  float t = a;
  t += __shfl_xor(t, 1); t += __shfl_xor(t, 2);  t += __shfl_xor(t, 4);
  t += __shfl_xor(t, 8); t += __shfl_xor(t, 16); t += __shfl_xor(t, 32);
  if (lane == 0) red[wid] = t;
  __syncthreads();
  float mu = (red[0] + red[1] + red[2] + red[3]) * (1.f / 256.f);
  float dv = a - mu;
  float t2 = dv * dv;
  t2 += __shfl_xor(t2, 1); t2 += __shfl_xor(t2, 2);  t2 += __shfl_xor(t2, 4);
  t2 += __shfl_xor(t2, 8); t2 += __shfl_xor(t2, 16); t2 += __shfl_xor(t2, 32);
  if (lane == 0) red[4 + wid] = t2;
  __syncthreads();
  float var = (red[4] + red[5] + red[6] + red[7]) * (1.f / 256.f);
  float o = ws[O_LNG + df] * dv / sqrtf(var + 1e-5f) + ws[O_LNB + df];
  size_t idx = ((size_t)(b * 1024 + p)) * 256 + df;
  if (F) ((ushortb*)out)[idx] = f2bf(o);
  else   ((float*)out)[idx]   = o;
}

// ---------------- launch ----------------
extern "C" void kernel_launch(void* const* d_in, const int* in_sizes, int n_in,
                              void* d_out, int out_size, void* d_ws, size_t ws_size,
                              hipStream_t stream)
{
  (void)in_sizes; (void)n_in; (void)out_size; (void)ws_size;
  const void* img   = d_in[0];
  const void* lang  = d_in[1];
  const void* c1w   = d_in[2];
  const void* c1b   = d_in[3];
  const void* c2w   = d_in[4];
  const void* c2b   = d_in[5];
  const void* fcw   = d_in[6];
  const void* fcb   = d_in[7];
  const void* wgate = d_in[8];
  const void* wgp   = d_in[9];
  const void* alog  = d_in[10];
  const void* dvec  = d_in[11];
  const void* bw    = d_in[12];
  const void* bb    = d_in[13];
  const void* cw    = d_in[14];
  const void* cb    = d_in[15];
  const void* wdw   = d_in[16];
  const void* wdb   = d_in[17];
  const void* ow    = d_in[18];
  const void* ob    = d_in[19];
  const void* lng   = d_in[20];
  const void* lnb   = d_in[21];
  float* ws = (float*)d_ws;

  k_sniff<<<1, 256, 0, stream>>>(img, ws);
  k_convert<<<990 + 2048 + 256, 256, 0, stream>>>(c1w, c1b, c2w, c2b, fcw, fcb, alog, dvec,
                                                  bw, bb, cw, cb, wdw, wdb, ow, ob, lng, lnb,
                                                  lang, wgate, wgp, ws);
  k_patch<<<2048, 512, 0, stream>>>(img, ws, ws + O_FEATS);
  k_struct<<<2, 1024, 0, stream>>>(ws);
  k_xdelta<<<2048, 256, 0, stream>>>(ws);
  k_scan<<<NB * DFEAT, 256, 0, stream>>>(ws);
  k_outln<<<2048, 256, 0, stream>>>(ws, d_out);
}